// Round 13
// baseline (1207.096 us; speedup 1.0000x reference)
//
#include <hip/hip_runtime.h>

#define HH   112
#define WW   320
#define CIN_ 128
#define HW_  (HH * WW)        // 35840
#define CHUNK 32              // max pixels per queue item
#define NBLK 1024             // 4 blocks/CU x 256 CUs — all co-resident
#define NTHR 256

__device__ __forceinline__ float lrelu(float v) {
    return v >= 0.f ? v : 0.01f * v;
}

// ============================================================================
// Shared-memory union: phases are serialized by barriers, so they share LDS.
// max member = 35200 B -> 4 blocks/CU (4 x 35.2KB = 141KB <= 160KB).
// ============================================================================
union SharedU {
    struct {                                  // phase 1 (stage-1 conv chain)
        float w1s0[32][CIN_ + 1];
        float w1s1[32][33];
        float w1s2[16][33];
        float b1s[80];
        float xT[16][132];
        float ysk[4][4][32];
    } p1;                                     // 33664 B
    struct {                                  // sorter phases
        int cnt[256];
        int scan[256];
        int rank[256];
    } ps;                                     // 3072 B
    struct {                                  // qk phases
        float ws0[CIN_ * 32];
        float ws1[32 * 32];
        float ws2[32 * 32];
        float bs[96];
        float xbuf[16][CIN_];
        float ys[4][4][32];
    } pq;                                     // 35200 B
};

// ============================================================================
// Grid-wide barrier: sense-reversal generation counter, device-scope atomics.
// Correct across XCDs: __threadfence() release (writes back local L2) before
// arrival; acquire fence after release (invalidates) before proceeding.
// Requires all NBLK blocks co-resident (guaranteed by occupancy: LDS 35.2KB
// -> 4 blocks/CU, __launch_bounds__(256,4) -> <=128 VGPR).
// ============================================================================
__device__ __forceinline__ void grid_barrier(int* bar_cnt, int* bar_gen) {
    __syncthreads();
    if (threadIdx.x == 0) {
        __threadfence();                      // release block's global writes
        const int g = __hip_atomic_load(bar_gen, __ATOMIC_RELAXED,
                                        __HIP_MEMORY_SCOPE_AGENT);
        const int arrived = __hip_atomic_fetch_add(bar_cnt, 1, __ATOMIC_ACQ_REL,
                                                   __HIP_MEMORY_SCOPE_AGENT);
        if (arrived == NBLK - 1) {
            __hip_atomic_store(bar_cnt, 0, __ATOMIC_RELAXED,
                               __HIP_MEMORY_SCOPE_AGENT);
            __hip_atomic_fetch_add(bar_gen, 1, __ATOMIC_RELEASE,
                                   __HIP_MEMORY_SCOPE_AGENT);
        } else {
            while (__hip_atomic_load(bar_gen, __ATOMIC_ACQUIRE,
                                     __HIP_MEMORY_SCOPE_AGENT) == g) {
                __builtin_amdgcn_s_sleep(8);
            }
        }
        __threadfence();                      // acquire other blocks' writes
    }
    __syncthreads();
}

// ============================================================================
// Sorter phase (device fn, 256 threads, runtime BINS). Bucket-sort one line's
// pixels by clipped routing index; emit <=CHUNK-pixel items. Item order
// nondeterministic (atomics); item set + all outputs deterministic.
// ============================================================================
__device__ void sorter_phase(const int* __restrict__ inds_in, int BINS,
                             int* __restrict__ sorted, int4* __restrict__ queue,
                             int* __restrict__ qcount,
                             int* cnt, int* scan, int* rank, int h)
{
    const int tid = threadIdx.x, base = h * WW;
    const int clipmax = BINS - 1;
    if (tid < BINS) { cnt[tid] = 0; rank[tid] = 0; }
    __syncthreads();

    int c0 = -1, c1 = -1;
    {
        c0 = inds_in[base + tid];
        c0 = min(max(c0, 0), clipmax);
        atomicAdd(&cnt[c0], 1);
        if (tid < WW - NTHR) {
            c1 = inds_in[base + NTHR + tid];
            c1 = min(max(c1, 0), clipmax);
            atomicAdd(&cnt[c1], 1);
        }
    }
    __syncthreads();
    if (tid < BINS) scan[tid] = cnt[tid];
    __syncthreads();
    for (int s = 1; s < BINS; s <<= 1) {
        int v = 0;
        if (tid >= s && tid < BINS) v = scan[tid - s];
        __syncthreads();
        if (tid < BINS) scan[tid] += v;
        __syncthreads();
    }
    {
        int pos = (scan[c0] - cnt[c0]) + atomicAdd(&rank[c0], 1);
        sorted[base + pos] = base + tid;
        if (tid < WW - NTHR) {
            int pos1 = (scan[c1] - cnt[c1]) + atomicAdd(&rank[c1], 1);
            sorted[base + pos1] = base + NTHR + tid;
        }
    }
    if (tid < BINS && cnt[tid] > 0) {
        int offc = scan[tid] - cnt[tid];
        for (int s0 = 0; s0 < cnt[tid]; s0 += CHUNK) {
            int qi = atomicAdd(qcount, 1);
            queue[qi] = make_int4(h, tid, base + offc + s0,
                                  min(CHUNK, cnt[tid] - s0));
        }
    }
}

// ============================================================================
// QK round macro — byte-identical arithmetic to the proven round-9/12 kernel.
// ============================================================================
#define QK_ROUND(TB, PA, PB, PC, PD)                                           \
{                                                                              \
    float a0 = 0.f, a1 = 0.f, a2 = 0.f, a3 = 0.f;                              \
    _Pragma("unroll")                                                          \
    for (int i = 0; i < 64; i += 4) {                                          \
        const int ii = half * 64 + i;                                          \
        const float w0v = ws0[(ii + 0) * 32 + o];                              \
        const float w1v = ws0[(ii + 1) * 32 + o];                              \
        const float w2v = ws0[(ii + 2) * 32 + o];                              \
        const float w3v = ws0[(ii + 3) * 32 + o];                              \
        const float4 v0 = *reinterpret_cast<const float4*>(&xbuf[wave*4+0][ii]);\
        const float4 v1 = *reinterpret_cast<const float4*>(&xbuf[wave*4+1][ii]);\
        const float4 v2 = *reinterpret_cast<const float4*>(&xbuf[wave*4+2][ii]);\
        const float4 v3 = *reinterpret_cast<const float4*>(&xbuf[wave*4+3][ii]);\
        a0 += v0.x * w0v; a1 += v1.x * w0v; a2 += v2.x * w0v; a3 += v3.x * w0v;\
        a0 += v0.y * w1v; a1 += v1.y * w1v; a2 += v2.y * w1v; a3 += v3.y * w1v;\
        a0 += v0.z * w2v; a1 += v1.z * w2v; a2 += v2.z * w2v; a3 += v3.z * w2v;\
        a0 += v0.w * w3v; a1 += v1.w * w3v; a2 += v2.w * w3v; a3 += v3.w * w3v;\
    }                                                                          \
    a0 += __shfl_xor(a0, 32); a1 += __shfl_xor(a1, 32);                        \
    a2 += __shfl_xor(a2, 32); a3 += __shfl_xor(a3, 32);                        \
    ys[wave][0][o] = lrelu(a0 + bs[o]);                                        \
    ys[wave][1][o] = lrelu(a1 + bs[o]);                                        \
    ys[wave][2][o] = lrelu(a2 + bs[o]);                                        \
    ys[wave][3][o] = lrelu(a3 + bs[o]);                                        \
    a0 = a1 = a2 = a3 = 0.f;                                                   \
    _Pragma("unroll")                                                          \
    for (int i = 0; i < 32; i += 4) {                                          \
        const float w0v = ws1[(i + 0) * 32 + o];                               \
        const float w1v = ws1[(i + 1) * 32 + o];                               \
        const float w2v = ws1[(i + 2) * 32 + o];                               \
        const float w3v = ws1[(i + 3) * 32 + o];                               \
        const float4 y0 = *reinterpret_cast<const float4*>(&ys[wave][0][i]);   \
        const float4 y1 = *reinterpret_cast<const float4*>(&ys[wave][1][i]);   \
        const float4 y2 = *reinterpret_cast<const float4*>(&ys[wave][2][i]);   \
        const float4 y3 = *reinterpret_cast<const float4*>(&ys[wave][3][i]);   \
        a0 += y0.x * w0v; a1 += y1.x * w0v; a2 += y2.x * w0v; a3 += y3.x * w0v;\
        a0 += y0.y * w1v; a1 += y1.y * w1v; a2 += y2.y * w1v; a3 += y3.y * w1v;\
        a0 += y0.z * w2v; a1 += y1.z * w2v; a2 += y2.z * w2v; a3 += y3.z * w2v;\
        a0 += y0.w * w3v; a1 += y1.w * w3v; a2 += y2.w * w3v; a3 += y3.w * w3v;\
    }                                                                          \
    ys[wave][0][o] = lrelu(a0 + bs[32 + o]);                                   \
    ys[wave][1][o] = lrelu(a1 + bs[32 + o]);                                   \
    ys[wave][2][o] = lrelu(a2 + bs[32 + o]);                                   \
    ys[wave][3][o] = lrelu(a3 + bs[32 + o]);                                   \
    a0 = a1 = a2 = a3 = 0.f;                                                   \
    _Pragma("unroll")                                                          \
    for (int i = 0; i < 32; i += 4) {                                          \
        const float w0v = ws2[(i + 0) * 32 + o];                               \
        const float w1v = ws2[(i + 1) * 32 + o];                               \
        const float w2v = ws2[(i + 2) * 32 + o];                               \
        const float w3v = ws2[(i + 3) * 32 + o];                               \
        const float4 y0 = *reinterpret_cast<const float4*>(&ys[wave][0][i]);   \
        const float4 y1 = *reinterpret_cast<const float4*>(&ys[wave][1][i]);   \
        const float4 y2 = *reinterpret_cast<const float4*>(&ys[wave][2][i]);   \
        const float4 y3 = *reinterpret_cast<const float4*>(&ys[wave][3][i]);   \
        a0 += y0.x * w0v; a1 += y1.x * w0v; a2 += y2.x * w0v; a3 += y3.x * w0v;\
        a0 += y0.y * w1v; a1 += y1.y * w1v; a2 += y2.y * w1v; a3 += y3.y * w1v;\
        a0 += y0.z * w2v; a1 += y1.z * w2v; a2 += y2.z * w2v; a3 += y3.z * w2v;\
        a0 += y0.w * w3v; a1 += y1.w * w3v; a2 += y2.w * w3v; a3 += y3.w * w3v;\
    }                                                                          \
    float bv0 = a0 + bs[64 + o], bv1 = a1 + bs[64 + o];                        \
    float bv2 = a2 + bs[64 + o], bv3 = a3 + bs[64 + o];                        \
    int bi0 = o, bi1 = o, bi2 = o, bi3 = o;                                    \
    _Pragma("unroll")                                                          \
    for (int d = 1; d < 32; d <<= 1) {                                         \
        const float ov0 = __shfl_xor(bv0, d); const int oi0 = __shfl_xor(bi0, d);\
        const float ov1 = __shfl_xor(bv1, d); const int oi1 = __shfl_xor(bi1, d);\
        const float ov2 = __shfl_xor(bv2, d); const int oi2 = __shfl_xor(bi2, d);\
        const float ov3 = __shfl_xor(bv3, d); const int oi3 = __shfl_xor(bi3, d);\
        if (ov0 > bv0 || (ov0 == bv0 && oi0 < bi0)) { bv0 = ov0; bi0 = oi0; }  \
        if (ov1 > bv1 || (ov1 == bv1 && oi1 < bi1)) { bv1 = ov1; bi1 = oi1; }  \
        if (ov2 > bv2 || (ov2 == bv2 && oi2 < bi2)) { bv2 = ov2; bi2 = oi2; }  \
        if (ov3 > bv3 || (ov3 == bv3 && oi3 < bi3)) { bv3 = ov3; bi3 = oi3; }  \
    }                                                                          \
    if (lane == 0) {                                                           \
        const int tb4 = (TB) + wave * 4;                                       \
        if (STAGE == 2) {                                                      \
            if (tb4 + 0 < n) result[PA] = c * 16 + bi0 - 8;                    \
            if (tb4 + 1 < n) result[PB] = c * 16 + bi1 - 8;                    \
            if (tb4 + 2 < n) result[PC] = c * 16 + bi2 - 8;                    \
            if (tb4 + 3 < n) result[PD] = c * 16 + bi3 - 8;                    \
        } else {                                                               \
            if (tb4 + 0 < n) result[PA] = min(max(inds12_in[PA] * 16 + bi0 - 8, 0), 4095); \
            if (tb4 + 1 < n) result[PB] = min(max(inds12_in[PB] * 16 + bi1 - 8, 0), 4095); \
            if (tb4 + 2 < n) result[PC] = min(max(inds12_in[PC] * 16 + bi2 - 8, 0), 4095); \
            if (tb4 + 3 < n) result[PD] = min(max(inds12_in[PD] * 16 + bi3 - 8, 0), 4095); \
        }                                                                      \
    }                                                                          \
}

template <int STAGE>
__device__ void qk_phase(const float* __restrict__ xT_in,
                         const int* __restrict__ sorted,
                         const int4* __restrict__ queue,
                         const int* __restrict__ qcount,
                         const float* __restrict__ W0, const float* __restrict__ Bb0,
                         const float* __restrict__ W1, const float* __restrict__ Bb1,
                         const float* __restrict__ W2, const float* __restrict__ Bb2,
                         const int* __restrict__ inds12_in, int* __restrict__ result,
                         float* ws0, float* ws1, float* ws2, float* bs,
                         float (*xbuf)[CIN_], float (*ys)[4][32])
{
    const int tid  = threadIdx.x;
    const int wave = tid >> 6;
    const int lane = tid & 63;
    const int o    = lane & 31;
    const int half = lane >> 5;

    const int qn = *qcount;
    for (int qi = blockIdx.x; qi < qn; qi += NBLK) {
        const int4 it4   = queue[qi];
        const int  c     = it4.y;
        const int  start = it4.z;
        const int  n     = it4.w;
        const int  key   = (STAGE == 2) ? (it4.x * 16 + c) : (it4.x * 256 + c);
        const int  nr    = (n + 15) >> 4;
        const int  t0    = wave * 4;

        __syncthreads();                  // all waves done with previous item's LDS

        const int pA0 = sorted[start + min(t0 + 0, n - 1)];
        const int pB0 = sorted[start + min(t0 + 1, n - 1)];
        const int pC0 = sorted[start + min(t0 + 2, n - 1)];
        const int pD0 = sorted[start + min(t0 + 3, n - 1)];
        const float2 xA0 = *reinterpret_cast<const float2*>(&xT_in[(size_t)pA0 * CIN_ + 2 * lane]);
        const float2 xB0 = *reinterpret_cast<const float2*>(&xT_in[(size_t)pB0 * CIN_ + 2 * lane]);
        const float2 xC0 = *reinterpret_cast<const float2*>(&xT_in[(size_t)pC0 * CIN_ + 2 * lane]);
        const float2 xD0 = *reinterpret_cast<const float2*>(&xT_in[(size_t)pD0 * CIN_ + 2 * lane]);

        for (int i = tid; i < 1024; i += NTHR)
            ((float4*)ws0)[i] = ((const float4*)(W0 + (size_t)key * 4096))[i];
        ((float4*)ws1)[tid] = ((const float4*)(W1 + (size_t)key * 1024))[tid];
        ((float4*)ws2)[tid] = ((const float4*)(W2 + (size_t)key * 1024))[tid];
        if      (tid < 32) bs[tid] = Bb0[(size_t)key * 32 + tid];
        else if (tid < 64) bs[tid] = Bb1[(size_t)key * 32 + (tid - 32)];
        else if (tid < 96) bs[tid] = Bb2[(size_t)key * 32 + (tid - 64)];
        __syncthreads();

        *reinterpret_cast<float2*>(&xbuf[wave * 4 + 0][2 * lane]) = xA0;
        *reinterpret_cast<float2*>(&xbuf[wave * 4 + 1][2 * lane]) = xB0;
        *reinterpret_cast<float2*>(&xbuf[wave * 4 + 2][2 * lane]) = xC0;
        *reinterpret_cast<float2*>(&xbuf[wave * 4 + 3][2 * lane]) = xD0;

        int pA1 = 0, pB1 = 0, pC1 = 0, pD1 = 0;
        float2 xA1 = {0.f, 0.f}, xB1 = {0.f, 0.f}, xC1 = {0.f, 0.f}, xD1 = {0.f, 0.f};
        if (nr == 2) {
            pA1 = sorted[start + min(16 + t0 + 0, n - 1)];
            pB1 = sorted[start + min(16 + t0 + 1, n - 1)];
            pC1 = sorted[start + min(16 + t0 + 2, n - 1)];
            pD1 = sorted[start + min(16 + t0 + 3, n - 1)];
            xA1 = *reinterpret_cast<const float2*>(&xT_in[(size_t)pA1 * CIN_ + 2 * lane]);
            xB1 = *reinterpret_cast<const float2*>(&xT_in[(size_t)pB1 * CIN_ + 2 * lane]);
            xC1 = *reinterpret_cast<const float2*>(&xT_in[(size_t)pC1 * CIN_ + 2 * lane]);
            xD1 = *reinterpret_cast<const float2*>(&xT_in[(size_t)pD1 * CIN_ + 2 * lane]);
        }

        QK_ROUND(0, pA0, pB0, pC0, pD0)

        if (nr == 2) {
            *reinterpret_cast<float2*>(&xbuf[wave * 4 + 0][2 * lane]) = xA1;
            *reinterpret_cast<float2*>(&xbuf[wave * 4 + 1][2 * lane]) = xB1;
            *reinterpret_cast<float2*>(&xbuf[wave * 4 + 2][2 * lane]) = xC1;
            *reinterpret_cast<float2*>(&xbuf[wave * 4 + 3][2 * lane]) = xD1;
            QK_ROUND(16, pA1, pB1, pC1, pD1)
        }
    }
}

// ============================================================================
// THE fused kernel: all 5 phases, grid barriers between them.
// ============================================================================
__global__ __launch_bounds__(NTHR, 4)
void fused_all(const float* __restrict__ x_in,
               const float* __restrict__ w1_0, const float* __restrict__ b1_0,
               const float* __restrict__ w1_1, const float* __restrict__ b1_1,
               const float* __restrict__ w1_2, const float* __restrict__ b1_2,
               const float* __restrict__ w2_0, const float* __restrict__ b2_0,
               const float* __restrict__ w2_1, const float* __restrict__ b2_1,
               const float* __restrict__ w2_2, const float* __restrict__ b2_2,
               const float* __restrict__ w3_0, const float* __restrict__ b3_0,
               const float* __restrict__ w3_1, const float* __restrict__ b3_1,
               const float* __restrict__ w3_2, const float* __restrict__ b3_2,
               int* __restrict__ inds1_ws, int* __restrict__ inds12_ws,
               int* __restrict__ sorted2, int* __restrict__ sorted3,
               int* __restrict__ ctrl,            // [qc2, qc3, bar_cnt, bar_gen]
               int4* __restrict__ queue2, int4* __restrict__ queue3,
               float* __restrict__ xT_ws, int* __restrict__ out)
{
    __shared__ SharedU sh;

    const int bid = blockIdx.x;
    const int tid = threadIdx.x;
    int* qc2     = ctrl + 0;
    int* qc3     = ctrl + 1;
    int* bar_cnt = ctrl + 2;
    int* bar_gen = ctrl + 3;

    // ===================== phase 1: stage-1 conv chain =====================
    {
        const int wave = tid >> 6;
        const int lane = tid & 63;
        const int o    = lane & 31;
        const int half = lane >> 5;
        const int o16  = lane & 15;

        const int i0 = (bid * (HH * 20)) / NBLK;
        const int i1 = ((bid + 1) * (HH * 20)) / NBLK;
        int hprev = -1;
        for (int it = i0; it < i1; ++it) {
            const int h = it / 20;
            const int t = it % 20;
            const int base = h * WW;
            const int w0 = t * 16;
            __syncthreads();                  // protect LDS from prev item readers
            if (h != hprev) {
                for (int n = tid; n < 32 * CIN_; n += NTHR)
                    sh.p1.w1s0[n >> 7][n & 127] = w1_0[h * (32 * CIN_) + n];
                for (int n = tid; n < 1024; n += NTHR)
                    sh.p1.w1s1[n >> 5][n & 31] = w1_1[h * 1024 + n];
                for (int n = tid; n < 512; n += NTHR)
                    sh.p1.w1s2[n >> 5][n & 31] = w1_2[h * 512 + n];
                if      (tid < 32) sh.p1.b1s[tid] = b1_0[h * 32 + tid];
                else if (tid < 64) sh.p1.b1s[tid] = b1_1[h * 32 + (tid - 32)];
                else if (tid < 80) sh.p1.b1s[tid] = b1_2[h * 16 + (tid - 64)];
                hprev = h;
            }
            for (int n = tid; n < 16 * CIN_; n += NTHR) {
                int ww = n & 15, cc = n >> 4;
                sh.p1.xT[ww][cc] = x_in[cc * HW_ + base + w0 + ww];
            }
            __syncthreads();
            for (int n = tid; n < 16 * CIN_; n += NTHR) {
                int pix = n >> 7, cc = n & 127;
                xT_ws[(size_t)(base + w0 + pix) * CIN_ + cc] = sh.p1.xT[pix][cc];
            }

            // layer1 128->32, 4 chains (bit-exact order)
            float a0 = 0.f, a1 = 0.f, a2 = 0.f, a3 = 0.f;
            #pragma unroll
            for (int i = 0; i < 64; i += 4) {
                const int ii = half * 64 + i;
                const float w0v = sh.p1.w1s0[o][ii];
                const float w1v = sh.p1.w1s0[o][ii + 1];
                const float w2v = sh.p1.w1s0[o][ii + 2];
                const float w3v = sh.p1.w1s0[o][ii + 3];
                const float4 v0 = *reinterpret_cast<const float4*>(&sh.p1.xT[wave * 4 + 0][ii]);
                const float4 v1 = *reinterpret_cast<const float4*>(&sh.p1.xT[wave * 4 + 1][ii]);
                const float4 v2 = *reinterpret_cast<const float4*>(&sh.p1.xT[wave * 4 + 2][ii]);
                const float4 v3 = *reinterpret_cast<const float4*>(&sh.p1.xT[wave * 4 + 3][ii]);
                a0 += v0.x * w0v; a1 += v1.x * w0v; a2 += v2.x * w0v; a3 += v3.x * w0v;
                a0 += v0.y * w1v; a1 += v1.y * w1v; a2 += v2.y * w1v; a3 += v3.y * w1v;
                a0 += v0.z * w2v; a1 += v1.z * w2v; a2 += v2.z * w2v; a3 += v3.z * w2v;
                a0 += v0.w * w3v; a1 += v1.w * w3v; a2 += v2.w * w3v; a3 += v3.w * w3v;
            }
            a0 += __shfl_xor(a0, 32); a1 += __shfl_xor(a1, 32);
            a2 += __shfl_xor(a2, 32); a3 += __shfl_xor(a3, 32);
            sh.p1.ysk[wave][0][o] = lrelu(a0 + sh.p1.b1s[o]);
            sh.p1.ysk[wave][1][o] = lrelu(a1 + sh.p1.b1s[o]);
            sh.p1.ysk[wave][2][o] = lrelu(a2 + sh.p1.b1s[o]);
            sh.p1.ysk[wave][3][o] = lrelu(a3 + sh.p1.b1s[o]);

            // layer2 32->32
            a0 = a1 = a2 = a3 = 0.f;
            #pragma unroll
            for (int i = 0; i < 32; i += 4) {
                const float w0v = sh.p1.w1s1[o][i];
                const float w1v = sh.p1.w1s1[o][i + 1];
                const float w2v = sh.p1.w1s1[o][i + 2];
                const float w3v = sh.p1.w1s1[o][i + 3];
                const float4 y0 = *reinterpret_cast<const float4*>(&sh.p1.ysk[wave][0][i]);
                const float4 y1 = *reinterpret_cast<const float4*>(&sh.p1.ysk[wave][1][i]);
                const float4 y2 = *reinterpret_cast<const float4*>(&sh.p1.ysk[wave][2][i]);
                const float4 y3 = *reinterpret_cast<const float4*>(&sh.p1.ysk[wave][3][i]);
                a0 += y0.x * w0v; a1 += y1.x * w0v; a2 += y2.x * w0v; a3 += y3.x * w0v;
                a0 += y0.y * w1v; a1 += y1.y * w1v; a2 += y2.y * w1v; a3 += y3.y * w1v;
                a0 += y0.z * w2v; a1 += y1.z * w2v; a2 += y2.z * w2v; a3 += y3.z * w2v;
                a0 += y0.w * w3v; a1 += y1.w * w3v; a2 += y2.w * w3v; a3 += y3.w * w3v;
            }
            sh.p1.ysk[wave][0][o] = lrelu(a0 + sh.p1.b1s[32 + o]);
            sh.p1.ysk[wave][1][o] = lrelu(a1 + sh.p1.b1s[32 + o]);
            sh.p1.ysk[wave][2][o] = lrelu(a2 + sh.p1.b1s[32 + o]);
            sh.p1.ysk[wave][3][o] = lrelu(a3 + sh.p1.b1s[32 + o]);

            // layer3 32->16
            a0 = a1 = a2 = a3 = 0.f;
            #pragma unroll
            for (int i = 0; i < 32; i += 4) {
                const float w0v = sh.p1.w1s2[o16][i];
                const float w1v = sh.p1.w1s2[o16][i + 1];
                const float w2v = sh.p1.w1s2[o16][i + 2];
                const float w3v = sh.p1.w1s2[o16][i + 3];
                const float4 y0 = *reinterpret_cast<const float4*>(&sh.p1.ysk[wave][0][i]);
                const float4 y1 = *reinterpret_cast<const float4*>(&sh.p1.ysk[wave][1][i]);
                const float4 y2 = *reinterpret_cast<const float4*>(&sh.p1.ysk[wave][2][i]);
                const float4 y3 = *reinterpret_cast<const float4*>(&sh.p1.ysk[wave][3][i]);
                a0 += y0.x * w0v; a1 += y1.x * w0v; a2 += y2.x * w0v; a3 += y3.x * w0v;
                a0 += y0.y * w1v; a1 += y1.y * w1v; a2 += y2.y * w1v; a3 += y3.y * w1v;
                a0 += y0.z * w2v; a1 += y1.z * w2v; a2 += y2.z * w2v; a3 += y3.z * w2v;
                a0 += y0.w * w3v; a1 += y1.w * w3v; a2 += y2.w * w3v; a3 += y3.w * w3v;
            }
            float bv0 = a0 + sh.p1.b1s[64 + o16], bv1 = a1 + sh.p1.b1s[64 + o16];
            float bv2 = a2 + sh.p1.b1s[64 + o16], bv3 = a3 + sh.p1.b1s[64 + o16];
            int bi0 = o16, bi1 = o16, bi2 = o16, bi3 = o16;
            #pragma unroll
            for (int d = 1; d < 16; d <<= 1) {
                const float ov0 = __shfl_xor(bv0, d); const int oi0 = __shfl_xor(bi0, d);
                const float ov1 = __shfl_xor(bv1, d); const int oi1 = __shfl_xor(bi1, d);
                const float ov2 = __shfl_xor(bv2, d); const int oi2 = __shfl_xor(bi2, d);
                const float ov3 = __shfl_xor(bv3, d); const int oi3 = __shfl_xor(bi3, d);
                if (ov0 > bv0 || (ov0 == bv0 && oi0 < bi0)) { bv0 = ov0; bi0 = oi0; }
                if (ov1 > bv1 || (ov1 == bv1 && oi1 < bi1)) { bv1 = ov1; bi1 = oi1; }
                if (ov2 > bv2 || (ov2 == bv2 && oi2 < bi2)) { bv2 = ov2; bi2 = oi2; }
                if (ov3 > bv3 || (ov3 == bv3 && oi3 < bi3)) { bv3 = ov3; bi3 = oi3; }
            }
            if (lane == 0) {
                inds1_ws[base + w0 + wave * 4 + 0] = bi0;
                inds1_ws[base + w0 + wave * 4 + 1] = bi1;
                inds1_ws[base + w0 + wave * 4 + 2] = bi2;
                inds1_ws[base + w0 + wave * 4 + 3] = bi3;
            }
        }
    }

    grid_barrier(bar_cnt, bar_gen);

    // ===================== phase 2: sorter for stage 2 =====================
    if (bid < HH)
        sorter_phase(inds1_ws, 16, sorted2, queue2, qc2,
                     sh.ps.cnt, sh.ps.scan, sh.ps.rank, bid);

    grid_barrier(bar_cnt, bar_gen);

    // ===================== phase 3: stage-2 CondMul chain ==================
    qk_phase<2>(xT_ws, sorted2, queue2, qc2,
                w2_0, b2_0, w2_1, b2_1, w2_2, b2_2, nullptr, inds12_ws,
                sh.pq.ws0, sh.pq.ws1, sh.pq.ws2, sh.pq.bs, sh.pq.xbuf, sh.pq.ys);

    grid_barrier(bar_cnt, bar_gen);

    // ===================== phase 4: sorter for stage 3 =====================
    if (bid < HH)
        sorter_phase(inds12_ws, 256, sorted3, queue3, qc3,
                     sh.ps.cnt, sh.ps.scan, sh.ps.rank, bid);

    grid_barrier(bar_cnt, bar_gen);

    // ===================== phase 5: stage-3 CondMul chain ==================
    qk_phase<3>(xT_ws, sorted3, queue3, qc3,
                w3_0, b3_0, w3_1, b3_1, w3_2, b3_2, inds12_ws, out,
                sh.pq.ws0, sh.pq.ws1, sh.pq.ws2, sh.pq.bs, sh.pq.xbuf, sh.pq.ys);
}

// ============================================================================
// Fallback: proven monolithic kernel (only if d_ws too small — not expected).
// ============================================================================
__global__ __launch_bounds__(512, 4)
void reg3_fused(const float* __restrict__ x_in,
                const float* __restrict__ w1_0, const float* __restrict__ b1_0,
                const float* __restrict__ w1_1, const float* __restrict__ b1_1,
                const float* __restrict__ w1_2, const float* __restrict__ b1_2,
                const float* __restrict__ w2_0, const float* __restrict__ b2_0,
                const float* __restrict__ w2_1, const float* __restrict__ b2_1,
                const float* __restrict__ w2_2, const float* __restrict__ b2_2,
                const float* __restrict__ w3_0, const float* __restrict__ b3_0,
                const float* __restrict__ w3_1, const float* __restrict__ b3_1,
                const float* __restrict__ w3_2, const float* __restrict__ b3_2,
                int* __restrict__ out)
{
    __shared__ float xT[8][CIN_ + 1];
    __shared__ float w1s0[32][CIN_ + 1];
    __shared__ float w1s1[32][33];
    __shared__ float w1s2[16][33];
    __shared__ float b1s[80];

    const int h   = blockIdx.x / 40;
    const int w0  = (blockIdx.x % 40) * 8;
    const int tid = threadIdx.x;

    for (int n = tid; n < 8 * CIN_; n += 512) {
        int ww = n & 7, c = n >> 3;
        xT[ww][c] = x_in[c * HW_ + h * WW + w0 + ww];
    }
    for (int n = tid; n < 32 * CIN_; n += 512)
        w1s0[n >> 7][n & 127] = w1_0[h * (32 * CIN_) + n];
    for (int n = tid; n < 32 * 32; n += 512)
        w1s1[n >> 5][n & 31] = w1_1[h * 1024 + n];
    if (tid < 16 * 32)
        w1s2[tid >> 5][tid & 31] = w1_2[h * 512 + tid];
    if      (tid < 32) b1s[tid] = b1_0[h * 32 + tid];
    else if (tid < 64) b1s[tid] = b1_1[h * 32 + (tid - 32)];
    else if (tid < 80) b1s[tid] = b1_2[h * 16 + (tid - 64)];
    __syncthreads();

    const int wave = tid >> 6, lane = tid & 63;
    const int o = lane & 31, half = lane >> 5, o16 = lane & 15;
    const float* xr = &xT[wave][0];

    float acc = 0.f;
    #pragma unroll
    for (int i = 0; i < 64; ++i) { int ii = half * 64 + i; acc += xr[ii] * w1s0[o][ii]; }
    acc += __shfl_xor(acc, 32);
    float y = lrelu(acc + b1s[o]);
    acc = 0.f;
    #pragma unroll
    for (int i = 0; i < 32; ++i) acc += __shfl(y, i) * w1s1[o][i];
    float y2 = lrelu(acc + b1s[32 + o]);
    acc = 0.f;
    #pragma unroll
    for (int i = 0; i < 32; ++i) acc += __shfl(y2, i) * w1s2[o16][i];
    float t1 = acc + b1s[64 + o16];

    float bv = t1; int bi = o16;
    #pragma unroll
    for (int d = 1; d < 16; d <<= 1) {
        float ov = __shfl_xor(bv, d); int oi = __shfl_xor(bi, d);
        if (ov > bv || (ov == bv && oi < bi)) { bv = ov; bi = oi; }
    }
    const int inds1 = bi;
    const int idx1  = inds1 + 16 * h;

    const float* Wp = w2_0 + (size_t)idx1 * (CIN_ * 32);
    acc = 0.f;
    #pragma unroll
    for (int i = 0; i < 64; ++i) { int ii = half * 64 + i; acc += xr[ii] * Wp[ii * 32 + o]; }
    acc += __shfl_xor(acc, 32);
    y = lrelu(acc + b2_0[idx1 * 32 + o]);
    Wp = w2_1 + (size_t)idx1 * 1024;
    acc = 0.f;
    #pragma unroll
    for (int i = 0; i < 32; ++i) acc += __shfl(y, i) * Wp[i * 32 + o];
    y2 = lrelu(acc + b2_1[idx1 * 32 + o]);
    Wp = w2_2 + (size_t)idx1 * 1024;
    acc = 0.f;
    #pragma unroll
    for (int i = 0; i < 32; ++i) acc += __shfl(y2, i) * Wp[i * 32 + o];
    float y3 = acc + b2_2[idx1 * 32 + o];

    bv = y3; bi = o;
    #pragma unroll
    for (int d = 1; d < 32; d <<= 1) {
        float ov = __shfl_xor(bv, d); int oi = __shfl_xor(bi, d);
        if (ov > bv || (ov == bv && oi < bi)) { bv = ov; bi = oi; }
    }
    const int inds2  = bi;
    const int inds12 = inds1 * 16 + inds2 - 8;
    const int clip12 = min(max(inds12, 0), 255);
    const int idx12  = clip12 + 256 * h;

    Wp = w3_0 + (size_t)idx12 * (CIN_ * 32);
    acc = 0.f;
    #pragma unroll
    for (int i = 0; i < 64; ++i) { int ii = half * 64 + i; acc += xr[ii] * Wp[ii * 32 + o]; }
    acc += __shfl_xor(acc, 32);
    y = lrelu(acc + b3_0[idx12 * 32 + o]);
    Wp = w3_1 + (size_t)idx12 * 1024;
    acc = 0.f;
    #pragma unroll
    for (int i = 0; i < 32; ++i) acc += __shfl(y, i) * Wp[i * 32 + o];
    y2 = lrelu(acc + b3_1[idx12 * 32 + o]);
    Wp = w3_2 + (size_t)idx12 * 1024;
    acc = 0.f;
    #pragma unroll
    for (int i = 0; i < 32; ++i) acc += __shfl(y2, i) * Wp[i * 32 + o];
    y3 = acc + b3_2[idx12 * 32 + o];

    bv = y3; bi = o;
    #pragma unroll
    for (int d = 1; d < 32; d <<= 1) {
        float ov = __shfl_xor(bv, d); int oi = __shfl_xor(bi, d);
        if (ov > bv || (ov == bv && oi < bi)) { bv = ov; bi = oi; }
    }
    int inds123 = inds12 * 16 + bi - 8;
    inds123 = min(max(inds123, 0), 4095);
    if (lane == 0) out[h * WW + w0 + wave] = inds123;
}

extern "C" void kernel_launch(void* const* d_in, const int* in_sizes, int n_in,
                              void* d_out, int out_size, void* d_ws, size_t ws_size,
                              hipStream_t stream)
{
    const float* x_in = (const float*)d_in[0];
    const float* w1_0 = (const float*)d_in[1];
    const float* b1_0 = (const float*)d_in[2];
    const float* w1_1 = (const float*)d_in[3];
    const float* b1_1 = (const float*)d_in[4];
    const float* w1_2 = (const float*)d_in[5];
    const float* b1_2 = (const float*)d_in[6];
    const float* w2_0 = (const float*)d_in[7];
    const float* b2_0 = (const float*)d_in[8];
    const float* w2_1 = (const float*)d_in[9];
    const float* b2_1 = (const float*)d_in[10];
    const float* w2_2 = (const float*)d_in[11];
    const float* b2_2 = (const float*)d_in[12];
    const float* w3_0 = (const float*)d_in[13];
    const float* b3_0 = (const float*)d_in[14];
    const float* w3_1 = (const float*)d_in[15];
    const float* b3_1 = (const float*)d_in[16];
    const float* w3_2 = (const float*)d_in[17];
    const float* b3_2 = (const float*)d_in[18];
    int* out = (int*)d_out;

    // ws layout (bytes)
    char* ws = (char*)d_ws;
    int*   inds1_ws  = (int*)(ws + 0);                 // HW ints
    int*   inds12_ws = (int*)(ws + 143360);            // HW ints
    int*   sorted2   = (int*)(ws + 286720);            // HW ints
    int*   sorted3   = (int*)(ws + 430080);            // HW ints
    int*   ctrl      = (int*)(ws + 573440);            // qc2,qc3,bar_cnt,bar_gen
    int4*  queue2    = (int4*)(ws + 573456);           // HW entries max
    int4*  queue3    = (int4*)(ws + 1146896);          // HW entries max
    float* xT_ws     = (float*)(ws + 1720336);         // HW*128 floats
    const size_t NEED = 1720336 + (size_t)HW_ * CIN_ * 4;   // ~20.07 MB

    if (ws_size >= NEED) {
        hipMemsetAsync(ctrl, 0, 16, stream);           // zero counters + barrier
        fused_all<<<NBLK, NTHR, 0, stream>>>(
            x_in, w1_0, b1_0, w1_1, b1_1, w1_2, b1_2,
            w2_0, b2_0, w2_1, b2_1, w2_2, b2_2,
            w3_0, b3_0, w3_1, b3_1, w3_2, b3_2,
            inds1_ws, inds12_ws, sorted2, sorted3, ctrl,
            queue2, queue3, xT_ws, out);
    } else {
        reg3_fused<<<HH * 40, 512, 0, stream>>>(
            x_in, w1_0, b1_0, w1_1, b1_1, w1_2, b1_2,
            w2_0, b2_0, w2_1, b2_1, w2_2, b2_2,
            w3_0, b3_0, w3_1, b3_1, w3_2, b3_2, out);
    }
}

// Round 14
// 630.604 us; speedup vs baseline: 1.9142x; 1.9142x over previous
//
#include <hip/hip_runtime.h>

#define HH   112
#define WW   320
#define CIN_ 128
#define HW_  (HH * WW)        // 35840
#define CHUNK 32              // max pixels per queue item
#define NBLK 512              // 2 blocks/CU x 256 CUs — co-residency GUARANTEED
#define NTHR 256              //   (2 x 35.3KB LDS = 70.6 <= 160KB; VGPR<=256 ok)

__device__ __forceinline__ float lrelu(float v) {
    return v >= 0.f ? v : 0.01f * v;
}

// ============================================================================
// Shared-memory union: phases are serialized by barriers, so they share LDS.
// ============================================================================
union SharedU {
    struct {                                  // phase 1 (stage-1 conv chain)
        float w1s0[32][CIN_ + 1];
        float w1s1[32][33];
        float w1s2[16][33];
        float b1s[80];
        float xT[16][132];
        float ysk[4][4][32];
    } p1;                                     // 33664 B
    struct {                                  // sorter phases
        int cnt[256];
        int scan[256];
        int rank[256];
    } ps;                                     // 3072 B
    struct {                                  // qk phases
        float ws0[CIN_ * 32];
        float ws1[32 * 32];
        float ws2[32 * 32];
        float bs[96];
        float xbuf[16][CIN_];
        float ys[4][4][32];
    } pq;                                     // 35200 B
};

// ============================================================================
// Grid-wide barrier: sense-reversal generation counter, device-scope atomics.
// __threadfence() release before arrival; acquire after release. Requires all
// NBLK blocks co-resident — guaranteed: 512 blocks = 2/CU, LDS 70.6KB/CU,
// and 8 waves/CU fits at any VGPR <= 256 (launch_bounds min-waves=2).
// Round-13 validated this barrier bit-exact incl. post-timing replays.
// ============================================================================
__device__ __forceinline__ void grid_barrier(int* bar_cnt, int* bar_gen) {
    __syncthreads();
    if (threadIdx.x == 0) {
        __threadfence();                      // release block's global writes
        const int g = __hip_atomic_load(bar_gen, __ATOMIC_RELAXED,
                                        __HIP_MEMORY_SCOPE_AGENT);
        const int arrived = __hip_atomic_fetch_add(bar_cnt, 1, __ATOMIC_ACQ_REL,
                                                   __HIP_MEMORY_SCOPE_AGENT);
        if (arrived == NBLK - 1) {
            __hip_atomic_store(bar_cnt, 0, __ATOMIC_RELAXED,
                               __HIP_MEMORY_SCOPE_AGENT);
            __hip_atomic_fetch_add(bar_gen, 1, __ATOMIC_RELEASE,
                                   __HIP_MEMORY_SCOPE_AGENT);
        } else {
            while (__hip_atomic_load(bar_gen, __ATOMIC_ACQUIRE,
                                     __HIP_MEMORY_SCOPE_AGENT) == g) {
                __builtin_amdgcn_s_sleep(8);
            }
        }
        __threadfence();                      // acquire other blocks' writes
    }
    __syncthreads();
}

// ============================================================================
// Sorter phase (256 threads, runtime BINS). Bucket-sort one line's pixels by
// clipped routing index; emit <=CHUNK-pixel items. Item order nondeterministic
// (atomics); item set + all outputs deterministic.
// ============================================================================
__device__ void sorter_phase(const int* __restrict__ inds_in, int BINS,
                             int* __restrict__ sorted, int4* __restrict__ queue,
                             int* __restrict__ qcount,
                             int* cnt, int* scan, int* rank, int h)
{
    const int tid = threadIdx.x, base = h * WW;
    const int clipmax = BINS - 1;
    if (tid < BINS) { cnt[tid] = 0; rank[tid] = 0; }
    __syncthreads();

    int c0 = -1, c1 = -1;
    {
        c0 = inds_in[base + tid];
        c0 = min(max(c0, 0), clipmax);
        atomicAdd(&cnt[c0], 1);
        if (tid < WW - NTHR) {
            c1 = inds_in[base + NTHR + tid];
            c1 = min(max(c1, 0), clipmax);
            atomicAdd(&cnt[c1], 1);
        }
    }
    __syncthreads();
    if (tid < BINS) scan[tid] = cnt[tid];
    __syncthreads();
    for (int s = 1; s < BINS; s <<= 1) {
        int v = 0;
        if (tid >= s && tid < BINS) v = scan[tid - s];
        __syncthreads();
        if (tid < BINS) scan[tid] += v;
        __syncthreads();
    }
    {
        int pos = (scan[c0] - cnt[c0]) + atomicAdd(&rank[c0], 1);
        sorted[base + pos] = base + tid;
        if (tid < WW - NTHR) {
            int pos1 = (scan[c1] - cnt[c1]) + atomicAdd(&rank[c1], 1);
            sorted[base + pos1] = base + NTHR + tid;
        }
    }
    if (tid < BINS && cnt[tid] > 0) {
        int offc = scan[tid] - cnt[tid];
        for (int s0 = 0; s0 < cnt[tid]; s0 += CHUNK) {
            int qi = atomicAdd(qcount, 1);
            queue[qi] = make_int4(h, tid, base + offc + s0,
                                  min(CHUNK, cnt[tid] - s0));
        }
    }
}

// ============================================================================
// QK round macro — byte-identical arithmetic to the proven round-9/12 kernel.
// ============================================================================
#define QK_ROUND(TB, PA, PB, PC, PD)                                           \
{                                                                              \
    float a0 = 0.f, a1 = 0.f, a2 = 0.f, a3 = 0.f;                              \
    _Pragma("unroll")                                                          \
    for (int i = 0; i < 64; i += 4) {                                          \
        const int ii = half * 64 + i;                                          \
        const float w0v = ws0[(ii + 0) * 32 + o];                              \
        const float w1v = ws0[(ii + 1) * 32 + o];                              \
        const float w2v = ws0[(ii + 2) * 32 + o];                              \
        const float w3v = ws0[(ii + 3) * 32 + o];                              \
        const float4 v0 = *reinterpret_cast<const float4*>(&xbuf[wave*4+0][ii]);\
        const float4 v1 = *reinterpret_cast<const float4*>(&xbuf[wave*4+1][ii]);\
        const float4 v2 = *reinterpret_cast<const float4*>(&xbuf[wave*4+2][ii]);\
        const float4 v3 = *reinterpret_cast<const float4*>(&xbuf[wave*4+3][ii]);\
        a0 += v0.x * w0v; a1 += v1.x * w0v; a2 += v2.x * w0v; a3 += v3.x * w0v;\
        a0 += v0.y * w1v; a1 += v1.y * w1v; a2 += v2.y * w1v; a3 += v3.y * w1v;\
        a0 += v0.z * w2v; a1 += v1.z * w2v; a2 += v2.z * w2v; a3 += v3.z * w2v;\
        a0 += v0.w * w3v; a1 += v1.w * w3v; a2 += v2.w * w3v; a3 += v3.w * w3v;\
    }                                                                          \
    a0 += __shfl_xor(a0, 32); a1 += __shfl_xor(a1, 32);                        \
    a2 += __shfl_xor(a2, 32); a3 += __shfl_xor(a3, 32);                        \
    ys[wave][0][o] = lrelu(a0 + bs[o]);                                        \
    ys[wave][1][o] = lrelu(a1 + bs[o]);                                        \
    ys[wave][2][o] = lrelu(a2 + bs[o]);                                        \
    ys[wave][3][o] = lrelu(a3 + bs[o]);                                        \
    a0 = a1 = a2 = a3 = 0.f;                                                   \
    _Pragma("unroll")                                                          \
    for (int i = 0; i < 32; i += 4) {                                          \
        const float w0v = ws1[(i + 0) * 32 + o];                               \
        const float w1v = ws1[(i + 1) * 32 + o];                               \
        const float w2v = ws1[(i + 2) * 32 + o];                               \
        const float w3v = ws1[(i + 3) * 32 + o];                               \
        const float4 y0 = *reinterpret_cast<const float4*>(&ys[wave][0][i]);   \
        const float4 y1 = *reinterpret_cast<const float4*>(&ys[wave][1][i]);   \
        const float4 y2 = *reinterpret_cast<const float4*>(&ys[wave][2][i]);   \
        const float4 y3 = *reinterpret_cast<const float4*>(&ys[wave][3][i]);   \
        a0 += y0.x * w0v; a1 += y1.x * w0v; a2 += y2.x * w0v; a3 += y3.x * w0v;\
        a0 += y0.y * w1v; a1 += y1.y * w1v; a2 += y2.y * w1v; a3 += y3.y * w1v;\
        a0 += y0.z * w2v; a1 += y1.z * w2v; a2 += y2.z * w2v; a3 += y3.z * w2v;\
        a0 += y0.w * w3v; a1 += y1.w * w3v; a2 += y2.w * w3v; a3 += y3.w * w3v;\
    }                                                                          \
    ys[wave][0][o] = lrelu(a0 + bs[32 + o]);                                   \
    ys[wave][1][o] = lrelu(a1 + bs[32 + o]);                                   \
    ys[wave][2][o] = lrelu(a2 + bs[32 + o]);                                   \
    ys[wave][3][o] = lrelu(a3 + bs[32 + o]);                                   \
    a0 = a1 = a2 = a3 = 0.f;                                                   \
    _Pragma("unroll")                                                          \
    for (int i = 0; i < 32; i += 4) {                                          \
        const float w0v = ws2[(i + 0) * 32 + o];                               \
        const float w1v = ws2[(i + 1) * 32 + o];                               \
        const float w2v = ws2[(i + 2) * 32 + o];                               \
        const float w3v = ws2[(i + 3) * 32 + o];                               \
        const float4 y0 = *reinterpret_cast<const float4*>(&ys[wave][0][i]);   \
        const float4 y1 = *reinterpret_cast<const float4*>(&ys[wave][1][i]);   \
        const float4 y2 = *reinterpret_cast<const float4*>(&ys[wave][2][i]);   \
        const float4 y3 = *reinterpret_cast<const float4*>(&ys[wave][3][i]);   \
        a0 += y0.x * w0v; a1 += y1.x * w0v; a2 += y2.x * w0v; a3 += y3.x * w0v;\
        a0 += y0.y * w1v; a1 += y1.y * w1v; a2 += y2.y * w1v; a3 += y3.y * w1v;\
        a0 += y0.z * w2v; a1 += y1.z * w2v; a2 += y2.z * w2v; a3 += y3.z * w2v;\
        a0 += y0.w * w3v; a1 += y1.w * w3v; a2 += y2.w * w3v; a3 += y3.w * w3v;\
    }                                                                          \
    float bv0 = a0 + bs[64 + o], bv1 = a1 + bs[64 + o];                        \
    float bv2 = a2 + bs[64 + o], bv3 = a3 + bs[64 + o];                        \
    int bi0 = o, bi1 = o, bi2 = o, bi3 = o;                                    \
    _Pragma("unroll")                                                          \
    for (int d = 1; d < 32; d <<= 1) {                                         \
        const float ov0 = __shfl_xor(bv0, d); const int oi0 = __shfl_xor(bi0, d);\
        const float ov1 = __shfl_xor(bv1, d); const int oi1 = __shfl_xor(bi1, d);\
        const float ov2 = __shfl_xor(bv2, d); const int oi2 = __shfl_xor(bi2, d);\
        const float ov3 = __shfl_xor(bv3, d); const int oi3 = __shfl_xor(bi3, d);\
        if (ov0 > bv0 || (ov0 == bv0 && oi0 < bi0)) { bv0 = ov0; bi0 = oi0; }  \
        if (ov1 > bv1 || (ov1 == bv1 && oi1 < bi1)) { bv1 = ov1; bi1 = oi1; }  \
        if (ov2 > bv2 || (ov2 == bv2 && oi2 < bi2)) { bv2 = ov2; bi2 = oi2; }  \
        if (ov3 > bv3 || (ov3 == bv3 && oi3 < bi3)) { bv3 = ov3; bi3 = oi3; }  \
    }                                                                          \
    if (lane == 0) {                                                           \
        const int tb4 = (TB) + wave * 4;                                       \
        if (STAGE == 2) {                                                      \
            if (tb4 + 0 < n) result[PA] = c * 16 + bi0 - 8;                    \
            if (tb4 + 1 < n) result[PB] = c * 16 + bi1 - 8;                    \
            if (tb4 + 2 < n) result[PC] = c * 16 + bi2 - 8;                    \
            if (tb4 + 3 < n) result[PD] = c * 16 + bi3 - 8;                    \
        } else {                                                               \
            if (tb4 + 0 < n) result[PA] = min(max(inds12_in[PA] * 16 + bi0 - 8, 0), 4095); \
            if (tb4 + 1 < n) result[PB] = min(max(inds12_in[PB] * 16 + bi1 - 8, 0), 4095); \
            if (tb4 + 2 < n) result[PC] = min(max(inds12_in[PC] * 16 + bi2 - 8, 0), 4095); \
            if (tb4 + 3 < n) result[PD] = min(max(inds12_in[PD] * 16 + bi3 - 8, 0), 4095); \
        }                                                                      \
    }                                                                          \
}

template <int STAGE>
__device__ void qk_phase(const float* __restrict__ xT_in,
                         const int* __restrict__ sorted,
                         const int4* __restrict__ queue,
                         const int* __restrict__ qcount,
                         const float* __restrict__ W0, const float* __restrict__ Bb0,
                         const float* __restrict__ W1, const float* __restrict__ Bb1,
                         const float* __restrict__ W2, const float* __restrict__ Bb2,
                         const int* __restrict__ inds12_in, int* __restrict__ result,
                         float* ws0, float* ws1, float* ws2, float* bs,
                         float (*xbuf)[CIN_], float (*ys)[4][32])
{
    const int tid  = threadIdx.x;
    const int wave = tid >> 6;
    const int lane = tid & 63;
    const int o    = lane & 31;
    const int half = lane >> 5;

    const int qn = *qcount;
    for (int qi = blockIdx.x; qi < qn; qi += NBLK) {
        const int4 it4   = queue[qi];
        const int  c     = it4.y;
        const int  start = it4.z;
        const int  n     = it4.w;
        const int  key   = (STAGE == 2) ? (it4.x * 16 + c) : (it4.x * 256 + c);
        const int  nr    = (n + 15) >> 4;
        const int  t0    = wave * 4;

        __syncthreads();                  // all waves done with previous item's LDS

        const int pA0 = sorted[start + min(t0 + 0, n - 1)];
        const int pB0 = sorted[start + min(t0 + 1, n - 1)];
        const int pC0 = sorted[start + min(t0 + 2, n - 1)];
        const int pD0 = sorted[start + min(t0 + 3, n - 1)];
        const float2 xA0 = *reinterpret_cast<const float2*>(&xT_in[(size_t)pA0 * CIN_ + 2 * lane]);
        const float2 xB0 = *reinterpret_cast<const float2*>(&xT_in[(size_t)pB0 * CIN_ + 2 * lane]);
        const float2 xC0 = *reinterpret_cast<const float2*>(&xT_in[(size_t)pC0 * CIN_ + 2 * lane]);
        const float2 xD0 = *reinterpret_cast<const float2*>(&xT_in[(size_t)pD0 * CIN_ + 2 * lane]);

        for (int i = tid; i < 1024; i += NTHR)
            ((float4*)ws0)[i] = ((const float4*)(W0 + (size_t)key * 4096))[i];
        ((float4*)ws1)[tid] = ((const float4*)(W1 + (size_t)key * 1024))[tid];
        ((float4*)ws2)[tid] = ((const float4*)(W2 + (size_t)key * 1024))[tid];
        if      (tid < 32) bs[tid] = Bb0[(size_t)key * 32 + tid];
        else if (tid < 64) bs[tid] = Bb1[(size_t)key * 32 + (tid - 32)];
        else if (tid < 96) bs[tid] = Bb2[(size_t)key * 32 + (tid - 64)];
        __syncthreads();

        *reinterpret_cast<float2*>(&xbuf[wave * 4 + 0][2 * lane]) = xA0;
        *reinterpret_cast<float2*>(&xbuf[wave * 4 + 1][2 * lane]) = xB0;
        *reinterpret_cast<float2*>(&xbuf[wave * 4 + 2][2 * lane]) = xC0;
        *reinterpret_cast<float2*>(&xbuf[wave * 4 + 3][2 * lane]) = xD0;

        int pA1 = 0, pB1 = 0, pC1 = 0, pD1 = 0;
        float2 xA1 = {0.f, 0.f}, xB1 = {0.f, 0.f}, xC1 = {0.f, 0.f}, xD1 = {0.f, 0.f};
        if (nr == 2) {
            pA1 = sorted[start + min(16 + t0 + 0, n - 1)];
            pB1 = sorted[start + min(16 + t0 + 1, n - 1)];
            pC1 = sorted[start + min(16 + t0 + 2, n - 1)];
            pD1 = sorted[start + min(16 + t0 + 3, n - 1)];
            xA1 = *reinterpret_cast<const float2*>(&xT_in[(size_t)pA1 * CIN_ + 2 * lane]);
            xB1 = *reinterpret_cast<const float2*>(&xT_in[(size_t)pB1 * CIN_ + 2 * lane]);
            xC1 = *reinterpret_cast<const float2*>(&xT_in[(size_t)pC1 * CIN_ + 2 * lane]);
            xD1 = *reinterpret_cast<const float2*>(&xT_in[(size_t)pD1 * CIN_ + 2 * lane]);
        }

        QK_ROUND(0, pA0, pB0, pC0, pD0)

        if (nr == 2) {
            *reinterpret_cast<float2*>(&xbuf[wave * 4 + 0][2 * lane]) = xA1;
            *reinterpret_cast<float2*>(&xbuf[wave * 4 + 1][2 * lane]) = xB1;
            *reinterpret_cast<float2*>(&xbuf[wave * 4 + 2][2 * lane]) = xC1;
            *reinterpret_cast<float2*>(&xbuf[wave * 4 + 3][2 * lane]) = xD1;
            QK_ROUND(16, pA1, pB1, pC1, pD1)
        }
    }
}

// ============================================================================
// THE fused kernel: all 5 phases, grid barriers between them.
// launch_bounds(256, 2): VGPR cap ~256 -> NO spill (round-13's (256,4) forced
// VGPR=64 and spilled 120MB/dispatch -> 1.2ms). Co-residency: 512 blocks =
// 2/CU guaranteed at any VGPR<=256.
// ============================================================================
__global__ __launch_bounds__(NTHR, 2)
void fused_all(const float* __restrict__ x_in,
               const float* __restrict__ w1_0, const float* __restrict__ b1_0,
               const float* __restrict__ w1_1, const float* __restrict__ b1_1,
               const float* __restrict__ w1_2, const float* __restrict__ b1_2,
               const float* __restrict__ w2_0, const float* __restrict__ b2_0,
               const float* __restrict__ w2_1, const float* __restrict__ b2_1,
               const float* __restrict__ w2_2, const float* __restrict__ b2_2,
               const float* __restrict__ w3_0, const float* __restrict__ b3_0,
               const float* __restrict__ w3_1, const float* __restrict__ b3_1,
               const float* __restrict__ w3_2, const float* __restrict__ b3_2,
               int* __restrict__ inds1_ws, int* __restrict__ inds12_ws,
               int* __restrict__ sorted2, int* __restrict__ sorted3,
               int* __restrict__ ctrl,            // [qc2, qc3, bar_cnt, bar_gen]
               int4* __restrict__ queue2, int4* __restrict__ queue3,
               float* __restrict__ xT_ws, int* __restrict__ out)
{
    __shared__ SharedU sh;

    const int bid = blockIdx.x;
    const int tid = threadIdx.x;
    int* qc2     = ctrl + 0;
    int* qc3     = ctrl + 1;
    int* bar_cnt = ctrl + 2;
    int* bar_gen = ctrl + 3;

    // ===================== phase 1: stage-1 conv chain =====================
    {
        const int wave = tid >> 6;
        const int lane = tid & 63;
        const int o    = lane & 31;
        const int half = lane >> 5;
        const int o16  = lane & 15;

        const int i0 = (bid * (HH * 20)) / NBLK;
        const int i1 = ((bid + 1) * (HH * 20)) / NBLK;
        int hprev = -1;
        for (int it = i0; it < i1; ++it) {
            const int h = it / 20;
            const int t = it % 20;
            const int base = h * WW;
            const int w0 = t * 16;
            __syncthreads();                  // protect LDS from prev item readers
            if (h != hprev) {
                for (int n = tid; n < 32 * CIN_; n += NTHR)
                    sh.p1.w1s0[n >> 7][n & 127] = w1_0[h * (32 * CIN_) + n];
                for (int n = tid; n < 1024; n += NTHR)
                    sh.p1.w1s1[n >> 5][n & 31] = w1_1[h * 1024 + n];
                for (int n = tid; n < 512; n += NTHR)
                    sh.p1.w1s2[n >> 5][n & 31] = w1_2[h * 512 + n];
                if      (tid < 32) sh.p1.b1s[tid] = b1_0[h * 32 + tid];
                else if (tid < 64) sh.p1.b1s[tid] = b1_1[h * 32 + (tid - 32)];
                else if (tid < 80) sh.p1.b1s[tid] = b1_2[h * 16 + (tid - 64)];
                hprev = h;
            }
            for (int n = tid; n < 16 * CIN_; n += NTHR) {
                int ww = n & 15, cc = n >> 4;
                sh.p1.xT[ww][cc] = x_in[cc * HW_ + base + w0 + ww];
            }
            __syncthreads();
            for (int n = tid; n < 16 * CIN_; n += NTHR) {
                int pix = n >> 7, cc = n & 127;
                xT_ws[(size_t)(base + w0 + pix) * CIN_ + cc] = sh.p1.xT[pix][cc];
            }

            // layer1 128->32, 4 chains (bit-exact order)
            float a0 = 0.f, a1 = 0.f, a2 = 0.f, a3 = 0.f;
            #pragma unroll
            for (int i = 0; i < 64; i += 4) {
                const int ii = half * 64 + i;
                const float w0v = sh.p1.w1s0[o][ii];
                const float w1v = sh.p1.w1s0[o][ii + 1];
                const float w2v = sh.p1.w1s0[o][ii + 2];
                const float w3v = sh.p1.w1s0[o][ii + 3];
                const float4 v0 = *reinterpret_cast<const float4*>(&sh.p1.xT[wave * 4 + 0][ii]);
                const float4 v1 = *reinterpret_cast<const float4*>(&sh.p1.xT[wave * 4 + 1][ii]);
                const float4 v2 = *reinterpret_cast<const float4*>(&sh.p1.xT[wave * 4 + 2][ii]);
                const float4 v3 = *reinterpret_cast<const float4*>(&sh.p1.xT[wave * 4 + 3][ii]);
                a0 += v0.x * w0v; a1 += v1.x * w0v; a2 += v2.x * w0v; a3 += v3.x * w0v;
                a0 += v0.y * w1v; a1 += v1.y * w1v; a2 += v2.y * w1v; a3 += v3.y * w1v;
                a0 += v0.z * w2v; a1 += v1.z * w2v; a2 += v2.z * w2v; a3 += v3.z * w2v;
                a0 += v0.w * w3v; a1 += v1.w * w3v; a2 += v2.w * w3v; a3 += v3.w * w3v;
            }
            a0 += __shfl_xor(a0, 32); a1 += __shfl_xor(a1, 32);
            a2 += __shfl_xor(a2, 32); a3 += __shfl_xor(a3, 32);
            sh.p1.ysk[wave][0][o] = lrelu(a0 + sh.p1.b1s[o]);
            sh.p1.ysk[wave][1][o] = lrelu(a1 + sh.p1.b1s[o]);
            sh.p1.ysk[wave][2][o] = lrelu(a2 + sh.p1.b1s[o]);
            sh.p1.ysk[wave][3][o] = lrelu(a3 + sh.p1.b1s[o]);

            // layer2 32->32
            a0 = a1 = a2 = a3 = 0.f;
            #pragma unroll
            for (int i = 0; i < 32; i += 4) {
                const float w0v = sh.p1.w1s1[o][i];
                const float w1v = sh.p1.w1s1[o][i + 1];
                const float w2v = sh.p1.w1s1[o][i + 2];
                const float w3v = sh.p1.w1s1[o][i + 3];
                const float4 y0 = *reinterpret_cast<const float4*>(&sh.p1.ysk[wave][0][i]);
                const float4 y1 = *reinterpret_cast<const float4*>(&sh.p1.ysk[wave][1][i]);
                const float4 y2 = *reinterpret_cast<const float4*>(&sh.p1.ysk[wave][2][i]);
                const float4 y3 = *reinterpret_cast<const float4*>(&sh.p1.ysk[wave][3][i]);
                a0 += y0.x * w0v; a1 += y1.x * w0v; a2 += y2.x * w0v; a3 += y3.x * w0v;
                a0 += y0.y * w1v; a1 += y1.y * w1v; a2 += y2.y * w1v; a3 += y3.y * w1v;
                a0 += y0.z * w2v; a1 += y1.z * w2v; a2 += y2.z * w2v; a3 += y3.z * w2v;
                a0 += y0.w * w3v; a1 += y1.w * w3v; a2 += y2.w * w3v; a3 += y3.w * w3v;
            }
            sh.p1.ysk[wave][0][o] = lrelu(a0 + sh.p1.b1s[32 + o]);
            sh.p1.ysk[wave][1][o] = lrelu(a1 + sh.p1.b1s[32 + o]);
            sh.p1.ysk[wave][2][o] = lrelu(a2 + sh.p1.b1s[32 + o]);
            sh.p1.ysk[wave][3][o] = lrelu(a3 + sh.p1.b1s[32 + o]);

            // layer3 32->16
            a0 = a1 = a2 = a3 = 0.f;
            #pragma unroll
            for (int i = 0; i < 32; i += 4) {
                const float w0v = sh.p1.w1s2[o16][i];
                const float w1v = sh.p1.w1s2[o16][i + 1];
                const float w2v = sh.p1.w1s2[o16][i + 2];
                const float w3v = sh.p1.w1s2[o16][i + 3];
                const float4 y0 = *reinterpret_cast<const float4*>(&sh.p1.ysk[wave][0][i]);
                const float4 y1 = *reinterpret_cast<const float4*>(&sh.p1.ysk[wave][1][i]);
                const float4 y2 = *reinterpret_cast<const float4*>(&sh.p1.ysk[wave][2][i]);
                const float4 y3 = *reinterpret_cast<const float4*>(&sh.p1.ysk[wave][3][i]);
                a0 += y0.x * w0v; a1 += y1.x * w0v; a2 += y2.x * w0v; a3 += y3.x * w0v;
                a0 += y0.y * w1v; a1 += y1.y * w1v; a2 += y2.y * w1v; a3 += y3.y * w1v;
                a0 += y0.z * w2v; a1 += y1.z * w2v; a2 += y2.z * w2v; a3 += y3.z * w2v;
                a0 += y0.w * w3v; a1 += y1.w * w3v; a2 += y2.w * w3v; a3 += y3.w * w3v;
            }
            float bv0 = a0 + sh.p1.b1s[64 + o16], bv1 = a1 + sh.p1.b1s[64 + o16];
            float bv2 = a2 + sh.p1.b1s[64 + o16], bv3 = a3 + sh.p1.b1s[64 + o16];
            int bi0 = o16, bi1 = o16, bi2 = o16, bi3 = o16;
            #pragma unroll
            for (int d = 1; d < 16; d <<= 1) {
                const float ov0 = __shfl_xor(bv0, d); const int oi0 = __shfl_xor(bi0, d);
                const float ov1 = __shfl_xor(bv1, d); const int oi1 = __shfl_xor(bi1, d);
                const float ov2 = __shfl_xor(bv2, d); const int oi2 = __shfl_xor(bi2, d);
                const float ov3 = __shfl_xor(bv3, d); const int oi3 = __shfl_xor(bi3, d);
                if (ov0 > bv0 || (ov0 == bv0 && oi0 < bi0)) { bv0 = ov0; bi0 = oi0; }
                if (ov1 > bv1 || (ov1 == bv1 && oi1 < bi1)) { bv1 = ov1; bi1 = oi1; }
                if (ov2 > bv2 || (ov2 == bv2 && oi2 < bi2)) { bv2 = ov2; bi2 = oi2; }
                if (ov3 > bv3 || (ov3 == bv3 && oi3 < bi3)) { bv3 = ov3; bi3 = oi3; }
            }
            if (lane == 0) {
                inds1_ws[base + w0 + wave * 4 + 0] = bi0;
                inds1_ws[base + w0 + wave * 4 + 1] = bi1;
                inds1_ws[base + w0 + wave * 4 + 2] = bi2;
                inds1_ws[base + w0 + wave * 4 + 3] = bi3;
            }
        }
    }

    grid_barrier(bar_cnt, bar_gen);

    // ===================== phase 2: sorter for stage 2 =====================
    if (bid < HH)
        sorter_phase(inds1_ws, 16, sorted2, queue2, qc2,
                     sh.ps.cnt, sh.ps.scan, sh.ps.rank, bid);

    grid_barrier(bar_cnt, bar_gen);

    // ===================== phase 3: stage-2 CondMul chain ==================
    qk_phase<2>(xT_ws, sorted2, queue2, qc2,
                w2_0, b2_0, w2_1, b2_1, w2_2, b2_2, nullptr, inds12_ws,
                sh.pq.ws0, sh.pq.ws1, sh.pq.ws2, sh.pq.bs, sh.pq.xbuf, sh.pq.ys);

    grid_barrier(bar_cnt, bar_gen);

    // ===================== phase 4: sorter for stage 3 =====================
    if (bid < HH)
        sorter_phase(inds12_ws, 256, sorted3, queue3, qc3,
                     sh.ps.cnt, sh.ps.scan, sh.ps.rank, bid);

    grid_barrier(bar_cnt, bar_gen);

    // ===================== phase 5: stage-3 CondMul chain ==================
    qk_phase<3>(xT_ws, sorted3, queue3, qc3,
                w3_0, b3_0, w3_1, b3_1, w3_2, b3_2, inds12_ws, out,
                sh.pq.ws0, sh.pq.ws1, sh.pq.ws2, sh.pq.bs, sh.pq.xbuf, sh.pq.ys);
}

// ============================================================================
// Fallback: proven monolithic kernel (only if d_ws too small — not expected).
// ============================================================================
__global__ __launch_bounds__(512, 4)
void reg3_fused(const float* __restrict__ x_in,
                const float* __restrict__ w1_0, const float* __restrict__ b1_0,
                const float* __restrict__ w1_1, const float* __restrict__ b1_1,
                const float* __restrict__ w1_2, const float* __restrict__ b1_2,
                const float* __restrict__ w2_0, const float* __restrict__ b2_0,
                const float* __restrict__ w2_1, const float* __restrict__ b2_1,
                const float* __restrict__ w2_2, const float* __restrict__ b2_2,
                const float* __restrict__ w3_0, const float* __restrict__ b3_0,
                const float* __restrict__ w3_1, const float* __restrict__ b3_1,
                const float* __restrict__ w3_2, const float* __restrict__ b3_2,
                int* __restrict__ out)
{
    __shared__ float xT[8][CIN_ + 1];
    __shared__ float w1s0[32][CIN_ + 1];
    __shared__ float w1s1[32][33];
    __shared__ float w1s2[16][33];
    __shared__ float b1s[80];

    const int h   = blockIdx.x / 40;
    const int w0  = (blockIdx.x % 40) * 8;
    const int tid = threadIdx.x;

    for (int n = tid; n < 8 * CIN_; n += 512) {
        int ww = n & 7, c = n >> 3;
        xT[ww][c] = x_in[c * HW_ + h * WW + w0 + ww];
    }
    for (int n = tid; n < 32 * CIN_; n += 512)
        w1s0[n >> 7][n & 127] = w1_0[h * (32 * CIN_) + n];
    for (int n = tid; n < 32 * 32; n += 512)
        w1s1[n >> 5][n & 31] = w1_1[h * 1024 + n];
    if (tid < 16 * 32)
        w1s2[tid >> 5][tid & 31] = w1_2[h * 512 + tid];
    if      (tid < 32) b1s[tid] = b1_0[h * 32 + tid];
    else if (tid < 64) b1s[tid] = b1_1[h * 32 + (tid - 32)];
    else if (tid < 80) b1s[tid] = b1_2[h * 16 + (tid - 64)];
    __syncthreads();

    const int wave = tid >> 6, lane = tid & 63;
    const int o = lane & 31, half = lane >> 5, o16 = lane & 15;
    const float* xr = &xT[wave][0];

    float acc = 0.f;
    #pragma unroll
    for (int i = 0; i < 64; ++i) { int ii = half * 64 + i; acc += xr[ii] * w1s0[o][ii]; }
    acc += __shfl_xor(acc, 32);
    float y = lrelu(acc + b1s[o]);
    acc = 0.f;
    #pragma unroll
    for (int i = 0; i < 32; ++i) acc += __shfl(y, i) * w1s1[o][i];
    float y2 = lrelu(acc + b1s[32 + o]);
    acc = 0.f;
    #pragma unroll
    for (int i = 0; i < 32; ++i) acc += __shfl(y2, i) * w1s2[o16][i];
    float t1 = acc + b1s[64 + o16];

    float bv = t1; int bi = o16;
    #pragma unroll
    for (int d = 1; d < 16; d <<= 1) {
        float ov = __shfl_xor(bv, d); int oi = __shfl_xor(bi, d);
        if (ov > bv || (ov == bv && oi < bi)) { bv = ov; bi = oi; }
    }
    const int inds1 = bi;
    const int idx1  = inds1 + 16 * h;

    const float* Wp = w2_0 + (size_t)idx1 * (CIN_ * 32);
    acc = 0.f;
    #pragma unroll
    for (int i = 0; i < 64; ++i) { int ii = half * 64 + i; acc += xr[ii] * Wp[ii * 32 + o]; }
    acc += __shfl_xor(acc, 32);
    y = lrelu(acc + b2_0[idx1 * 32 + o]);
    Wp = w2_1 + (size_t)idx1 * 1024;
    acc = 0.f;
    #pragma unroll
    for (int i = 0; i < 32; ++i) acc += __shfl(y, i) * Wp[i * 32 + o];
    y2 = lrelu(acc + b2_1[idx1 * 32 + o]);
    Wp = w2_2 + (size_t)idx1 * 1024;
    acc = 0.f;
    #pragma unroll
    for (int i = 0; i < 32; ++i) acc += __shfl(y2, i) * Wp[i * 32 + o];
    float y3 = acc + b2_2[idx1 * 32 + o];

    bv = y3; bi = o;
    #pragma unroll
    for (int d = 1; d < 32; d <<= 1) {
        float ov = __shfl_xor(bv, d); int oi = __shfl_xor(bi, d);
        if (ov > bv || (ov == bv && oi < bi)) { bv = ov; bi = oi; }
    }
    const int inds2  = bi;
    const int inds12 = inds1 * 16 + inds2 - 8;
    const int clip12 = min(max(inds12, 0), 255);
    const int idx12  = clip12 + 256 * h;

    Wp = w3_0 + (size_t)idx12 * (CIN_ * 32);
    acc = 0.f;
    #pragma unroll
    for (int i = 0; i < 64; ++i) { int ii = half * 64 + i; acc += xr[ii] * Wp[ii * 32 + o]; }
    acc += __shfl_xor(acc, 32);
    y = lrelu(acc + b3_0[idx12 * 32 + o]);
    Wp = w3_1 + (size_t)idx12 * 1024;
    acc = 0.f;
    #pragma unroll
    for (int i = 0; i < 32; ++i) acc += __shfl(y, i) * Wp[i * 32 + o];
    y2 = lrelu(acc + b3_1[idx12 * 32 + o]);
    Wp = w3_2 + (size_t)idx12 * 1024;
    acc = 0.f;
    #pragma unroll
    for (int i = 0; i < 32; ++i) acc += __shfl(y2, i) * Wp[i * 32 + o];
    y3 = acc + b3_2[idx12 * 32 + o];

    bv = y3; bi = o;
    #pragma unroll
    for (int d = 1; d < 32; d <<= 1) {
        float ov = __shfl_xor(bv, d); int oi = __shfl_xor(bi, d);
        if (ov > bv || (ov == bv && oi < bi)) { bv = ov; bi = oi; }
    }
    int inds123 = inds12 * 16 + bi - 8;
    inds123 = min(max(inds123, 0), 4095);
    if (lane == 0) out[h * WW + w0 + wave] = inds123;
}

extern "C" void kernel_launch(void* const* d_in, const int* in_sizes, int n_in,
                              void* d_out, int out_size, void* d_ws, size_t ws_size,
                              hipStream_t stream)
{
    const float* x_in = (const float*)d_in[0];
    const float* w1_0 = (const float*)d_in[1];
    const float* b1_0 = (const float*)d_in[2];
    const float* w1_1 = (const float*)d_in[3];
    const float* b1_1 = (const float*)d_in[4];
    const float* w1_2 = (const float*)d_in[5];
    const float* b1_2 = (const float*)d_in[6];
    const float* w2_0 = (const float*)d_in[7];
    const float* b2_0 = (const float*)d_in[8];
    const float* w2_1 = (const float*)d_in[9];
    const float* b2_1 = (const float*)d_in[10];
    const float* w2_2 = (const float*)d_in[11];
    const float* b2_2 = (const float*)d_in[12];
    const float* w3_0 = (const float*)d_in[13];
    const float* b3_0 = (const float*)d_in[14];
    const float* w3_1 = (const float*)d_in[15];
    const float* b3_1 = (const float*)d_in[16];
    const float* w3_2 = (const float*)d_in[17];
    const float* b3_2 = (const float*)d_in[18];
    int* out = (int*)d_out;

    // ws layout (bytes)
    char* ws = (char*)d_ws;
    int*   inds1_ws  = (int*)(ws + 0);                 // HW ints
    int*   inds12_ws = (int*)(ws + 143360);            // HW ints
    int*   sorted2   = (int*)(ws + 286720);            // HW ints
    int*   sorted3   = (int*)(ws + 430080);            // HW ints
    int*   ctrl      = (int*)(ws + 573440);            // qc2,qc3,bar_cnt,bar_gen
    int4*  queue2    = (int4*)(ws + 573456);           // HW entries max
    int4*  queue3    = (int4*)(ws + 1146896);          // HW entries max
    float* xT_ws     = (float*)(ws + 1720336);         // HW*128 floats
    const size_t NEED = 1720336 + (size_t)HW_ * CIN_ * 4;   // ~20.07 MB

    if (ws_size >= NEED) {
        hipMemsetAsync(ctrl, 0, 16, stream);           // zero counters + barrier
        fused_all<<<NBLK, NTHR, 0, stream>>>(
            x_in, w1_0, b1_0, w1_1, b1_1, w1_2, b1_2,
            w2_0, b2_0, w2_1, b2_1, w2_2, b2_2,
            w3_0, b3_0, w3_1, b3_1, w3_2, b3_2,
            inds1_ws, inds12_ws, sorted2, sorted3, ctrl,
            queue2, queue3, xT_ws, out);
    } else {
        reg3_fused<<<HH * 40, 512, 0, stream>>>(
            x_in, w1_0, b1_0, w1_1, b1_1, w1_2, b1_2,
            w2_0, b2_0, w2_1, b2_1, w2_2, b2_2,
            w3_0, b3_0, w3_1, b3_1, w3_2, b3_2, out);
    }
}

// Round 15
// 257.542 us; speedup vs baseline: 4.6870x; 2.4485x over previous
//
#include <hip/hip_runtime.h>

#define HH   112
#define WW   320
#define CIN_ 128
#define HW_  (HH * WW)        // 35840
#define CHUNK 32              // max pixels per queue item (2 rounds of 16)

__device__ __forceinline__ float lrelu(float v) {
    return v >= 0.f ? v : 0.01f * v;
}

// ============================================================================
// In-kernel sorter (device fn). Bucket-sort one line's pixels by clipped
// routing index; emit <=CHUNK-pixel items {h,c,start,count} to the global
// queue. Within-bucket order + item order are atomic-nondeterministic (as in
// all proven rounds); per-pixel RESULTS are order-independent -> deterministic.
// ============================================================================
template <int BINS, int NT>
__device__ void sorter_dev(const int* __restrict__ inds_in,
                           int* __restrict__ sorted, int4* __restrict__ queue,
                           int* __restrict__ qcount,
                           int* cnt, int* scan, int* rank, int h)
{
    const int tid = threadIdx.x, base = h * WW;
    if (tid < BINS) { cnt[tid] = 0; rank[tid] = 0; }
    __syncthreads();
    for (int p = tid; p < WW; p += NT) {
        int c = inds_in[base + p];
        c = min(max(c, 0), BINS - 1);
        atomicAdd(&cnt[c], 1);
    }
    __syncthreads();
    if (tid < BINS) scan[tid] = cnt[tid];
    __syncthreads();
    for (int s = 1; s < BINS; s <<= 1) {
        int v = 0;
        if (tid >= s && tid < BINS) v = scan[tid - s];
        __syncthreads();
        if (tid < BINS) scan[tid] += v;
        __syncthreads();
    }
    for (int p = tid; p < WW; p += NT) {
        int c = inds_in[base + p];
        c = min(max(c, 0), BINS - 1);
        int pos = (scan[c] - cnt[c]) + atomicAdd(&rank[c], 1);
        sorted[base + pos] = base + p;            // absolute pixel id
    }
    if (tid < BINS && cnt[tid] > 0) {
        int offc = scan[tid] - cnt[tid];
        for (int s0 = 0; s0 < cnt[tid]; s0 += CHUNK) {
            int qi = atomicAdd(qcount, 1);
            queue[qi] = make_int4(h, tid, base + offc + s0,
                                  min(CHUNK, cnt[tid] - s0));
        }
    }
    __syncthreads();
}

// ============================================================================
// K1: stage 1 (round-12 proven 4-chain body) + fused per-line sorter<16>.
// 2 blocks per line; the SECOND block to finish a line sorts it.
// ============================================================================
__global__ __launch_bounds__(512, 2)
void k1_stage1(const float* __restrict__ x_in,
               const float* __restrict__ w1_0, const float* __restrict__ b1_0,
               const float* __restrict__ w1_1, const float* __restrict__ b1_1,
               const float* __restrict__ w1_2, const float* __restrict__ b1_2,
               int* __restrict__ inds1_out, float* __restrict__ xT_out,
               int* __restrict__ sorted2, int4* __restrict__ queue2,
               int* __restrict__ qc2, int* __restrict__ done1)
{
    __shared__ float w1s0[32][CIN_ + 1];
    __shared__ float w1s1[32][33];
    __shared__ float w1s2[16][33];
    __shared__ float b1s[80];
    __shared__ float xT[32][132];
    __shared__ float ys[8][4][32];
    __shared__ int kcnt[16], kscan[16], krank[16];
    __shared__ int kflag;

    const int h   = blockIdx.x >> 1;
    const int q   = blockIdx.x & 1;
    const int tid = threadIdx.x;
    const int base = h * WW;

    for (int n = tid; n < 32 * CIN_; n += 512)
        w1s0[n >> 7][n & 127] = w1_0[h * (32 * CIN_) + n];
    for (int n = tid; n < 32 * 32; n += 512)
        w1s1[n >> 5][n & 31] = w1_1[h * 1024 + n];
    if (tid < 16 * 32)
        w1s2[tid >> 5][tid & 31] = w1_2[h * 512 + tid];
    if      (tid < 32) b1s[tid] = b1_0[h * 32 + tid];
    else if (tid < 64) b1s[tid] = b1_1[h * 32 + (tid - 32)];
    else if (tid < 80) b1s[tid] = b1_2[h * 16 + (tid - 64)];
    __syncthreads();

    const int wave = tid >> 6;
    const int lane = tid & 63;
    const int o    = lane & 31;
    const int half = lane >> 5;
    const int o16  = lane & 15;

    for (int t = 0; t < 5; ++t) {
        const int w0 = q * 160 + t * 32;
        for (int n = tid; n < 32 * CIN_; n += 512) {
            int ww = n & 31, c = n >> 5;
            xT[ww][c] = x_in[c * HW_ + base + w0 + ww];
        }
        __syncthreads();
        for (int n = tid; n < 32 * CIN_; n += 512) {
            int pix = n >> 7, c = n & 127;
            xT_out[(size_t)(base + w0 + pix) * CIN_ + c] = xT[pix][c];
        }

        float a0 = 0.f, a1 = 0.f, a2 = 0.f, a3 = 0.f;
        #pragma unroll
        for (int i = 0; i < 64; i += 4) {
            const int ii = half * 64 + i;
            const float w0v = w1s0[o][ii];
            const float w1v = w1s0[o][ii + 1];
            const float w2v = w1s0[o][ii + 2];
            const float w3v = w1s0[o][ii + 3];
            const float4 v0 = *reinterpret_cast<const float4*>(&xT[wave * 4 + 0][ii]);
            const float4 v1 = *reinterpret_cast<const float4*>(&xT[wave * 4 + 1][ii]);
            const float4 v2 = *reinterpret_cast<const float4*>(&xT[wave * 4 + 2][ii]);
            const float4 v3 = *reinterpret_cast<const float4*>(&xT[wave * 4 + 3][ii]);
            a0 += v0.x * w0v; a1 += v1.x * w0v; a2 += v2.x * w0v; a3 += v3.x * w0v;
            a0 += v0.y * w1v; a1 += v1.y * w1v; a2 += v2.y * w1v; a3 += v3.y * w1v;
            a0 += v0.z * w2v; a1 += v1.z * w2v; a2 += v2.z * w2v; a3 += v3.z * w2v;
            a0 += v0.w * w3v; a1 += v1.w * w3v; a2 += v2.w * w3v; a3 += v3.w * w3v;
        }
        a0 += __shfl_xor(a0, 32); a1 += __shfl_xor(a1, 32);
        a2 += __shfl_xor(a2, 32); a3 += __shfl_xor(a3, 32);
        ys[wave][0][o] = lrelu(a0 + b1s[o]);
        ys[wave][1][o] = lrelu(a1 + b1s[o]);
        ys[wave][2][o] = lrelu(a2 + b1s[o]);
        ys[wave][3][o] = lrelu(a3 + b1s[o]);

        a0 = a1 = a2 = a3 = 0.f;
        #pragma unroll
        for (int i = 0; i < 32; i += 4) {
            const float w0v = w1s1[o][i];
            const float w1v = w1s1[o][i + 1];
            const float w2v = w1s1[o][i + 2];
            const float w3v = w1s1[o][i + 3];
            const float4 y0 = *reinterpret_cast<const float4*>(&ys[wave][0][i]);
            const float4 y1 = *reinterpret_cast<const float4*>(&ys[wave][1][i]);
            const float4 y2 = *reinterpret_cast<const float4*>(&ys[wave][2][i]);
            const float4 y3 = *reinterpret_cast<const float4*>(&ys[wave][3][i]);
            a0 += y0.x * w0v; a1 += y1.x * w0v; a2 += y2.x * w0v; a3 += y3.x * w0v;
            a0 += y0.y * w1v; a1 += y1.y * w1v; a2 += y2.y * w1v; a3 += y3.y * w1v;
            a0 += y0.z * w2v; a1 += y1.z * w2v; a2 += y2.z * w2v; a3 += y3.z * w2v;
            a0 += y0.w * w3v; a1 += y1.w * w3v; a2 += y2.w * w3v; a3 += y3.w * w3v;
        }
        ys[wave][0][o] = lrelu(a0 + b1s[32 + o]);
        ys[wave][1][o] = lrelu(a1 + b1s[32 + o]);
        ys[wave][2][o] = lrelu(a2 + b1s[32 + o]);
        ys[wave][3][o] = lrelu(a3 + b1s[32 + o]);

        a0 = a1 = a2 = a3 = 0.f;
        #pragma unroll
        for (int i = 0; i < 32; i += 4) {
            const float w0v = w1s2[o16][i];
            const float w1v = w1s2[o16][i + 1];
            const float w2v = w1s2[o16][i + 2];
            const float w3v = w1s2[o16][i + 3];
            const float4 y0 = *reinterpret_cast<const float4*>(&ys[wave][0][i]);
            const float4 y1 = *reinterpret_cast<const float4*>(&ys[wave][1][i]);
            const float4 y2 = *reinterpret_cast<const float4*>(&ys[wave][2][i]);
            const float4 y3 = *reinterpret_cast<const float4*>(&ys[wave][3][i]);
            a0 += y0.x * w0v; a1 += y1.x * w0v; a2 += y2.x * w0v; a3 += y3.x * w0v;
            a0 += y0.y * w1v; a1 += y1.y * w1v; a2 += y2.y * w1v; a3 += y3.y * w1v;
            a0 += y0.z * w2v; a1 += y1.z * w2v; a2 += y2.z * w2v; a3 += y3.z * w2v;
            a0 += y0.w * w3v; a1 += y1.w * w3v; a2 += y2.w * w3v; a3 += y3.w * w3v;
        }
        float bv0 = a0 + b1s[64 + o16], bv1 = a1 + b1s[64 + o16];
        float bv2 = a2 + b1s[64 + o16], bv3 = a3 + b1s[64 + o16];
        int bi0 = o16, bi1 = o16, bi2 = o16, bi3 = o16;
        #pragma unroll
        for (int d = 1; d < 16; d <<= 1) {
            const float ov0 = __shfl_xor(bv0, d); const int oi0 = __shfl_xor(bi0, d);
            const float ov1 = __shfl_xor(bv1, d); const int oi1 = __shfl_xor(bi1, d);
            const float ov2 = __shfl_xor(bv2, d); const int oi2 = __shfl_xor(bi2, d);
            const float ov3 = __shfl_xor(bv3, d); const int oi3 = __shfl_xor(bi3, d);
            if (ov0 > bv0 || (ov0 == bv0 && oi0 < bi0)) { bv0 = ov0; bi0 = oi0; }
            if (ov1 > bv1 || (ov1 == bv1 && oi1 < bi1)) { bv1 = ov1; bi1 = oi1; }
            if (ov2 > bv2 || (ov2 == bv2 && oi2 < bi2)) { bv2 = ov2; bi2 = oi2; }
            if (ov3 > bv3 || (ov3 == bv3 && oi3 < bi3)) { bv3 = ov3; bi3 = oi3; }
        }
        if (lane == 0) {
            inds1_out[base + w0 + wave * 4 + 0] = bi0;
            inds1_out[base + w0 + wave * 4 + 1] = bi1;
            inds1_out[base + w0 + wave * 4 + 2] = bi2;
            inds1_out[base + w0 + wave * 4 + 3] = bi3;
        }
        __syncthreads();
    }

    // ---- fused per-line sorter<16>: second block of the line runs it ----
    // __syncthreads above drained this block's stores to L2; tid0 fence
    // publishes device-wide (cross-XCD) before the release-add.
    if (tid == 0) {
        __threadfence();
        int prev = atomicAdd(&done1[h], 1);
        kflag = (prev == 1) ? 1 : 0;
    }
    __syncthreads();
    if (kflag) {
        __threadfence();                       // acquire other block's writes
        sorter_dev<16, 512>(inds1_out, sorted2, queue2, qc2,
                            kcnt, kscan, krank, h);
    }
}

// ============================================================================
// QK round macro — byte-identical arithmetic to the proven round-9/12 kernel.
// ============================================================================
#define QK_ROUND(TB, PA, PB, PC, PD)                                           \
{                                                                              \
    float a0 = 0.f, a1 = 0.f, a2 = 0.f, a3 = 0.f;                              \
    _Pragma("unroll")                                                          \
    for (int i = 0; i < 64; i += 4) {                                          \
        const int ii = half * 64 + i;                                          \
        const float w0v = ws0[(ii + 0) * 32 + o];                              \
        const float w1v = ws0[(ii + 1) * 32 + o];                              \
        const float w2v = ws0[(ii + 2) * 32 + o];                              \
        const float w3v = ws0[(ii + 3) * 32 + o];                              \
        const float4 v0 = *reinterpret_cast<const float4*>(&xbuf[wave*4+0][ii]);\
        const float4 v1 = *reinterpret_cast<const float4*>(&xbuf[wave*4+1][ii]);\
        const float4 v2 = *reinterpret_cast<const float4*>(&xbuf[wave*4+2][ii]);\
        const float4 v3 = *reinterpret_cast<const float4*>(&xbuf[wave*4+3][ii]);\
        a0 += v0.x * w0v; a1 += v1.x * w0v; a2 += v2.x * w0v; a3 += v3.x * w0v;\
        a0 += v0.y * w1v; a1 += v1.y * w1v; a2 += v2.y * w1v; a3 += v3.y * w1v;\
        a0 += v0.z * w2v; a1 += v1.z * w2v; a2 += v2.z * w2v; a3 += v3.z * w2v;\
        a0 += v0.w * w3v; a1 += v1.w * w3v; a2 += v2.w * w3v; a3 += v3.w * w3v;\
    }                                                                          \
    a0 += __shfl_xor(a0, 32); a1 += __shfl_xor(a1, 32);                        \
    a2 += __shfl_xor(a2, 32); a3 += __shfl_xor(a3, 32);                        \
    ys[wave][0][o] = lrelu(a0 + bs[o]);                                        \
    ys[wave][1][o] = lrelu(a1 + bs[o]);                                        \
    ys[wave][2][o] = lrelu(a2 + bs[o]);                                        \
    ys[wave][3][o] = lrelu(a3 + bs[o]);                                        \
    a0 = a1 = a2 = a3 = 0.f;                                                   \
    _Pragma("unroll")                                                          \
    for (int i = 0; i < 32; i += 4) {                                          \
        const float w0v = ws1[(i + 0) * 32 + o];                               \
        const float w1v = ws1[(i + 1) * 32 + o];                               \
        const float w2v = ws1[(i + 2) * 32 + o];                               \
        const float w3v = ws1[(i + 3) * 32 + o];                               \
        const float4 y0 = *reinterpret_cast<const float4*>(&ys[wave][0][i]);   \
        const float4 y1 = *reinterpret_cast<const float4*>(&ys[wave][1][i]);   \
        const float4 y2 = *reinterpret_cast<const float4*>(&ys[wave][2][i]);   \
        const float4 y3 = *reinterpret_cast<const float4*>(&ys[wave][3][i]);   \
        a0 += y0.x * w0v; a1 += y1.x * w0v; a2 += y2.x * w0v; a3 += y3.x * w0v;\
        a0 += y0.y * w1v; a1 += y1.y * w1v; a2 += y2.y * w1v; a3 += y3.y * w1v;\
        a0 += y0.z * w2v; a1 += y1.z * w2v; a2 += y2.z * w2v; a3 += y3.z * w2v;\
        a0 += y0.w * w3v; a1 += y1.w * w3v; a2 += y2.w * w3v; a3 += y3.w * w3v;\
    }                                                                          \
    ys[wave][0][o] = lrelu(a0 + bs[32 + o]);                                   \
    ys[wave][1][o] = lrelu(a1 + bs[32 + o]);                                   \
    ys[wave][2][o] = lrelu(a2 + bs[32 + o]);                                   \
    ys[wave][3][o] = lrelu(a3 + bs[32 + o]);                                   \
    a0 = a1 = a2 = a3 = 0.f;                                                   \
    _Pragma("unroll")                                                          \
    for (int i = 0; i < 32; i += 4) {                                          \
        const float w0v = ws2[(i + 0) * 32 + o];                               \
        const float w1v = ws2[(i + 1) * 32 + o];                               \
        const float w2v = ws2[(i + 2) * 32 + o];                               \
        const float w3v = ws2[(i + 3) * 32 + o];                               \
        const float4 y0 = *reinterpret_cast<const float4*>(&ys[wave][0][i]);   \
        const float4 y1 = *reinterpret_cast<const float4*>(&ys[wave][1][i]);   \
        const float4 y2 = *reinterpret_cast<const float4*>(&ys[wave][2][i]);   \
        const float4 y3 = *reinterpret_cast<const float4*>(&ys[wave][3][i]);   \
        a0 += y0.x * w0v; a1 += y1.x * w0v; a2 += y2.x * w0v; a3 += y3.x * w0v;\
        a0 += y0.y * w1v; a1 += y1.y * w1v; a2 += y2.y * w1v; a3 += y3.y * w1v;\
        a0 += y0.z * w2v; a1 += y1.z * w2v; a2 += y2.z * w2v; a3 += y3.z * w2v;\
        a0 += y0.w * w3v; a1 += y1.w * w3v; a2 += y2.w * w3v; a3 += y3.w * w3v;\
    }                                                                          \
    float bv0 = a0 + bs[64 + o], bv1 = a1 + bs[64 + o];                        \
    float bv2 = a2 + bs[64 + o], bv3 = a3 + bs[64 + o];                        \
    int bi0 = o, bi1 = o, bi2 = o, bi3 = o;                                    \
    _Pragma("unroll")                                                          \
    for (int d = 1; d < 32; d <<= 1) {                                         \
        const float ov0 = __shfl_xor(bv0, d); const int oi0 = __shfl_xor(bi0, d);\
        const float ov1 = __shfl_xor(bv1, d); const int oi1 = __shfl_xor(bi1, d);\
        const float ov2 = __shfl_xor(bv2, d); const int oi2 = __shfl_xor(bi2, d);\
        const float ov3 = __shfl_xor(bv3, d); const int oi3 = __shfl_xor(bi3, d);\
        if (ov0 > bv0 || (ov0 == bv0 && oi0 < bi0)) { bv0 = ov0; bi0 = oi0; }  \
        if (ov1 > bv1 || (ov1 == bv1 && oi1 < bi1)) { bv1 = ov1; bi1 = oi1; }  \
        if (ov2 > bv2 || (ov2 == bv2 && oi2 < bi2)) { bv2 = ov2; bi2 = oi2; }  \
        if (ov3 > bv3 || (ov3 == bv3 && oi3 < bi3)) { bv3 = ov3; bi3 = oi3; }  \
    }                                                                          \
    if (lane == 0) {                                                           \
        const int tb4 = (TB) + wave * 4;                                       \
        if (STAGE == 2) {                                                      \
            if (tb4 + 0 < n) result[PA] = c * 16 + bi0 - 8;                    \
            if (tb4 + 1 < n) result[PB] = c * 16 + bi1 - 8;                    \
            if (tb4 + 2 < n) result[PC] = c * 16 + bi2 - 8;                    \
            if (tb4 + 3 < n) result[PD] = c * 16 + bi3 - 8;                    \
        } else {                                                               \
            if (tb4 + 0 < n) result[PA] = min(max(inds12_in[PA] * 16 + bi0 - 8, 0), 4095); \
            if (tb4 + 1 < n) result[PB] = min(max(inds12_in[PB] * 16 + bi1 - 8, 0), 4095); \
            if (tb4 + 2 < n) result[PC] = min(max(inds12_in[PC] * 16 + bi2 - 8, 0), 4095); \
            if (tb4 + 3 < n) result[PD] = min(max(inds12_in[PD] * 16 + bi3 - 8, 0), 4095); \
        }                                                                      \
    }                                                                          \
}

// ============================================================================
// Queue-driven CondMul chain — round-12 proven body. DOSORT=1 (stage 2 only):
// per-line pixel-completion counter; the block completing a line runs the
// stage-3 sorter<256> for it inline.
// ============================================================================
template <int STAGE, int DOSORT>
__global__ __launch_bounds__(256, 4)
void qk_compute(const float* __restrict__ xT_in, const int* __restrict__ sorted,
                const int4* __restrict__ queue, const int* __restrict__ qcount,
                const float* __restrict__ W0, const float* __restrict__ Bb0,
                const float* __restrict__ W1, const float* __restrict__ Bb1,
                const float* __restrict__ W2, const float* __restrict__ Bb2,
                const int* __restrict__ inds12_in, int* __restrict__ result,
                int* __restrict__ done_px, int* __restrict__ s_sorted,
                int4* __restrict__ s_queue, int* __restrict__ s_qc)
{
    __shared__ float ws0[CIN_ * 32];
    __shared__ float ws1[32 * 32];
    __shared__ float ws2[32 * 32];
    __shared__ float bs[96];
    __shared__ float xbuf[16][CIN_];
    __shared__ float ys[4][4][32];
    __shared__ int scnt[DOSORT ? 256 : 1];
    __shared__ int sscan[DOSORT ? 256 : 1];
    __shared__ int srank[DOSORT ? 256 : 1];
    __shared__ int sline;

    const int tid  = threadIdx.x;
    const int wave = tid >> 6;
    const int lane = tid & 63;
    const int o    = lane & 31;
    const int half = lane >> 5;

    const int qn = *qcount;
    for (int qi = blockIdx.x; qi < qn; qi += gridDim.x) {
        const int4 it4   = queue[qi];
        const int  c     = it4.y;
        const int  start = it4.z;
        const int  n     = it4.w;
        const int  key   = (STAGE == 2) ? (it4.x * 16 + c) : (it4.x * 256 + c);
        const int  nr    = (n + 15) >> 4;
        const int  t0    = wave * 4;

        __syncthreads();                  // all waves done with previous item's LDS

        const int pA0 = sorted[start + min(t0 + 0, n - 1)];
        const int pB0 = sorted[start + min(t0 + 1, n - 1)];
        const int pC0 = sorted[start + min(t0 + 2, n - 1)];
        const int pD0 = sorted[start + min(t0 + 3, n - 1)];
        const float2 xA0 = *reinterpret_cast<const float2*>(&xT_in[(size_t)pA0 * CIN_ + 2 * lane]);
        const float2 xB0 = *reinterpret_cast<const float2*>(&xT_in[(size_t)pB0 * CIN_ + 2 * lane]);
        const float2 xC0 = *reinterpret_cast<const float2*>(&xT_in[(size_t)pC0 * CIN_ + 2 * lane]);
        const float2 xD0 = *reinterpret_cast<const float2*>(&xT_in[(size_t)pD0 * CIN_ + 2 * lane]);

        for (int i = tid; i < 1024; i += 256)
            ((float4*)ws0)[i] = ((const float4*)(W0 + (size_t)key * 4096))[i];
        ((float4*)ws1)[tid] = ((const float4*)(W1 + (size_t)key * 1024))[tid];
        ((float4*)ws2)[tid] = ((const float4*)(W2 + (size_t)key * 1024))[tid];
        if      (tid < 32) bs[tid] = Bb0[(size_t)key * 32 + tid];
        else if (tid < 64) bs[tid] = Bb1[(size_t)key * 32 + (tid - 32)];
        else if (tid < 96) bs[tid] = Bb2[(size_t)key * 32 + (tid - 64)];
        __syncthreads();

        *reinterpret_cast<float2*>(&xbuf[wave * 4 + 0][2 * lane]) = xA0;
        *reinterpret_cast<float2*>(&xbuf[wave * 4 + 1][2 * lane]) = xB0;
        *reinterpret_cast<float2*>(&xbuf[wave * 4 + 2][2 * lane]) = xC0;
        *reinterpret_cast<float2*>(&xbuf[wave * 4 + 3][2 * lane]) = xD0;

        int pA1 = 0, pB1 = 0, pC1 = 0, pD1 = 0;
        float2 xA1 = {0.f, 0.f}, xB1 = {0.f, 0.f}, xC1 = {0.f, 0.f}, xD1 = {0.f, 0.f};
        if (nr == 2) {
            pA1 = sorted[start + min(16 + t0 + 0, n - 1)];
            pB1 = sorted[start + min(16 + t0 + 1, n - 1)];
            pC1 = sorted[start + min(16 + t0 + 2, n - 1)];
            pD1 = sorted[start + min(16 + t0 + 3, n - 1)];
            xA1 = *reinterpret_cast<const float2*>(&xT_in[(size_t)pA1 * CIN_ + 2 * lane]);
            xB1 = *reinterpret_cast<const float2*>(&xT_in[(size_t)pB1 * CIN_ + 2 * lane]);
            xC1 = *reinterpret_cast<const float2*>(&xT_in[(size_t)pC1 * CIN_ + 2 * lane]);
            xD1 = *reinterpret_cast<const float2*>(&xT_in[(size_t)pD1 * CIN_ + 2 * lane]);
        }

        QK_ROUND(0, pA0, pB0, pC0, pD0)

        if (nr == 2) {
            *reinterpret_cast<float2*>(&xbuf[wave * 4 + 0][2 * lane]) = xA1;
            *reinterpret_cast<float2*>(&xbuf[wave * 4 + 1][2 * lane]) = xB1;
            *reinterpret_cast<float2*>(&xbuf[wave * 4 + 2][2 * lane]) = xC1;
            *reinterpret_cast<float2*>(&xbuf[wave * 4 + 3][2 * lane]) = xD1;
            QK_ROUND(16, pA1, pB1, pC1, pD1)
        }

        if (DOSORT) {
            // ---- per-line completion; finisher runs stage-3 sorter inline ----
            __syncthreads();              // drain this block's result stores
            if (tid == 0) {
                __threadfence();          // publish cross-XCD
                int d = atomicAdd(&done_px[it4.x], n) + n;
                sline = (d == WW) ? it4.x : -1;
            }
            __syncthreads();
            if (sline >= 0) {
                __threadfence();          // acquire other blocks' results
                sorter_dev<256, 256>(result, s_sorted, s_queue, s_qc,
                                     scnt, sscan, srank, sline);
            }
        }
    }
}

// ============================================================================
// Fallback: proven monolithic kernel (only if d_ws too small — not expected).
// ============================================================================
__global__ __launch_bounds__(512, 4)
void reg3_fused(const float* __restrict__ x_in,
                const float* __restrict__ w1_0, const float* __restrict__ b1_0,
                const float* __restrict__ w1_1, const float* __restrict__ b1_1,
                const float* __restrict__ w1_2, const float* __restrict__ b1_2,
                const float* __restrict__ w2_0, const float* __restrict__ b2_0,
                const float* __restrict__ w2_1, const float* __restrict__ b2_1,
                const float* __restrict__ w2_2, const float* __restrict__ b2_2,
                const float* __restrict__ w3_0, const float* __restrict__ b3_0,
                const float* __restrict__ w3_1, const float* __restrict__ b3_1,
                const float* __restrict__ w3_2, const float* __restrict__ b3_2,
                int* __restrict__ out)
{
    __shared__ float xT[8][CIN_ + 1];
    __shared__ float w1s0[32][CIN_ + 1];
    __shared__ float w1s1[32][33];
    __shared__ float w1s2[16][33];
    __shared__ float b1s[80];

    const int h   = blockIdx.x / 40;
    const int w0  = (blockIdx.x % 40) * 8;
    const int tid = threadIdx.x;

    for (int n = tid; n < 8 * CIN_; n += 512) {
        int ww = n & 7, c = n >> 3;
        xT[ww][c] = x_in[c * HW_ + h * WW + w0 + ww];
    }
    for (int n = tid; n < 32 * CIN_; n += 512)
        w1s0[n >> 7][n & 127] = w1_0[h * (32 * CIN_) + n];
    for (int n = tid; n < 32 * 32; n += 512)
        w1s1[n >> 5][n & 31] = w1_1[h * 1024 + n];
    if (tid < 16 * 32)
        w1s2[tid >> 5][tid & 31] = w1_2[h * 512 + tid];
    if      (tid < 32) b1s[tid] = b1_0[h * 32 + tid];
    else if (tid < 64) b1s[tid] = b1_1[h * 32 + (tid - 32)];
    else if (tid < 80) b1s[tid] = b1_2[h * 16 + (tid - 64)];
    __syncthreads();

    const int wave = tid >> 6, lane = tid & 63;
    const int o = lane & 31, half = lane >> 5, o16 = lane & 15;
    const float* xr = &xT[wave][0];

    float acc = 0.f;
    #pragma unroll
    for (int i = 0; i < 64; ++i) { int ii = half * 64 + i; acc += xr[ii] * w1s0[o][ii]; }
    acc += __shfl_xor(acc, 32);
    float y = lrelu(acc + b1s[o]);
    acc = 0.f;
    #pragma unroll
    for (int i = 0; i < 32; ++i) acc += __shfl(y, i) * w1s1[o][i];
    float y2 = lrelu(acc + b1s[32 + o]);
    acc = 0.f;
    #pragma unroll
    for (int i = 0; i < 32; ++i) acc += __shfl(y2, i) * w1s2[o16][i];
    float t1 = acc + b1s[64 + o16];

    float bv = t1; int bi = o16;
    #pragma unroll
    for (int d = 1; d < 16; d <<= 1) {
        float ov = __shfl_xor(bv, d); int oi = __shfl_xor(bi, d);
        if (ov > bv || (ov == bv && oi < bi)) { bv = ov; bi = oi; }
    }
    const int inds1 = bi;
    const int idx1  = inds1 + 16 * h;

    const float* Wp = w2_0 + (size_t)idx1 * (CIN_ * 32);
    acc = 0.f;
    #pragma unroll
    for (int i = 0; i < 64; ++i) { int ii = half * 64 + i; acc += xr[ii] * Wp[ii * 32 + o]; }
    acc += __shfl_xor(acc, 32);
    y = lrelu(acc + b2_0[idx1 * 32 + o]);
    Wp = w2_1 + (size_t)idx1 * 1024;
    acc = 0.f;
    #pragma unroll
    for (int i = 0; i < 32; ++i) acc += __shfl(y, i) * Wp[i * 32 + o];
    y2 = lrelu(acc + b2_1[idx1 * 32 + o]);
    Wp = w2_2 + (size_t)idx1 * 1024;
    acc = 0.f;
    #pragma unroll
    for (int i = 0; i < 32; ++i) acc += __shfl(y2, i) * Wp[i * 32 + o];
    float y3 = acc + b2_2[idx1 * 32 + o];

    bv = y3; bi = o;
    #pragma unroll
    for (int d = 1; d < 32; d <<= 1) {
        float ov = __shfl_xor(bv, d); int oi = __shfl_xor(bi, d);
        if (ov > bv || (ov == bv && oi < bi)) { bv = ov; bi = oi; }
    }
    const int inds2  = bi;
    const int inds12 = inds1 * 16 + inds2 - 8;
    const int clip12 = min(max(inds12, 0), 255);
    const int idx12  = clip12 + 256 * h;

    Wp = w3_0 + (size_t)idx12 * (CIN_ * 32);
    acc = 0.f;
    #pragma unroll
    for (int i = 0; i < 64; ++i) { int ii = half * 64 + i; acc += xr[ii] * Wp[ii * 32 + o]; }
    acc += __shfl_xor(acc, 32);
    y = lrelu(acc + b3_0[idx12 * 32 + o]);
    Wp = w3_1 + (size_t)idx12 * 1024;
    acc = 0.f;
    #pragma unroll
    for (int i = 0; i < 32; ++i) acc += __shfl(y, i) * Wp[i * 32 + o];
    y2 = lrelu(acc + b3_1[idx12 * 32 + o]);
    Wp = w3_2 + (size_t)idx12 * 1024;
    acc = 0.f;
    #pragma unroll
    for (int i = 0; i < 32; ++i) acc += __shfl(y2, i) * Wp[i * 32 + o];
    y3 = acc + b3_2[idx12 * 32 + o];

    bv = y3; bi = o;
    #pragma unroll
    for (int d = 1; d < 32; d <<= 1) {
        float ov = __shfl_xor(bv, d); int oi = __shfl_xor(bi, d);
        if (ov > bv || (ov == bv && oi < bi)) { bv = ov; bi = oi; }
    }
    int inds123 = inds12 * 16 + bi - 8;
    inds123 = min(max(inds123, 0), 4095);
    if (lane == 0) out[h * WW + w0 + wave] = inds123;
}

extern "C" void kernel_launch(void* const* d_in, const int* in_sizes, int n_in,
                              void* d_out, int out_size, void* d_ws, size_t ws_size,
                              hipStream_t stream)
{
    const float* x_in = (const float*)d_in[0];
    const float* w1_0 = (const float*)d_in[1];
    const float* b1_0 = (const float*)d_in[2];
    const float* w1_1 = (const float*)d_in[3];
    const float* b1_1 = (const float*)d_in[4];
    const float* w1_2 = (const float*)d_in[5];
    const float* b1_2 = (const float*)d_in[6];
    const float* w2_0 = (const float*)d_in[7];
    const float* b2_0 = (const float*)d_in[8];
    const float* w2_1 = (const float*)d_in[9];
    const float* b2_1 = (const float*)d_in[10];
    const float* w2_2 = (const float*)d_in[11];
    const float* b2_2 = (const float*)d_in[12];
    const float* w3_0 = (const float*)d_in[13];
    const float* b3_0 = (const float*)d_in[14];
    const float* w3_1 = (const float*)d_in[15];
    const float* b3_1 = (const float*)d_in[16];
    const float* w3_2 = (const float*)d_in[17];
    const float* b3_2 = (const float*)d_in[18];
    int* out = (int*)d_out;

    // ws layout (bytes)
    char* ws = (char*)d_ws;
    int*   inds1_ws  = (int*)(ws + 0);                 // HW ints
    int*   inds12_ws = (int*)(ws + 143360);            // HW ints
    int*   sorted2   = (int*)(ws + 286720);            // HW ints
    int*   sorted3   = (int*)(ws + 430080);            // HW ints
    int*   ctrl      = (int*)(ws + 573440);            // qc2,qc3,done1[112],done2[112]
    int4*  queue2    = (int4*)(ws + 574464);           // HW entries max
    int4*  queue3    = (int4*)(ws + 1147904);          // HW entries max
    float* xT_ws     = (float*)(ws + 1721344);         // HW*128 floats
    const size_t NEED = 1721344 + (size_t)HW_ * CIN_ * 4;   // ~20.07 MB

    int* qc2   = ctrl + 0;
    int* qc3   = ctrl + 1;
    int* done1 = ctrl + 2;          // 112 ints
    int* done2 = ctrl + 114;        // 112 ints

    if (ws_size >= NEED) {
        hipMemsetAsync(ctrl, 0, 1024, stream);   // zero qc2/qc3/done1/done2
        k1_stage1<<<HH * 2, 512, 0, stream>>>(
            x_in, w1_0, b1_0, w1_1, b1_1, w1_2, b1_2,
            inds1_ws, xT_ws, sorted2, queue2, qc2, done1);
        qk_compute<2, 1><<<2048, 256, 0, stream>>>(
            xT_ws, sorted2, queue2, qc2,
            w2_0, b2_0, w2_1, b2_1, w2_2, b2_2, nullptr, inds12_ws,
            done2, sorted3, queue3, qc3);
        qk_compute<3, 0><<<2048, 256, 0, stream>>>(
            xT_ws, sorted3, queue3, qc3,
            w3_0, b3_0, w3_1, b3_1, w3_2, b3_2, inds12_ws, out,
            nullptr, nullptr, nullptr, nullptr);
    } else {
        reg3_fused<<<HH * 40, 512, 0, stream>>>(
            x_in, w1_0, b1_0, w1_1, b1_1, w1_2, b1_2,
            w2_0, b2_0, w2_1, b2_1, w2_2, b2_2,
            w3_0, b3_0, w3_1, b3_1, w3_2, b3_2, out);
    }
}

// Round 16
// 181.034 us; speedup vs baseline: 6.6678x; 1.4226x over previous
//
#include <hip/hip_runtime.h>

#define HH   112
#define WW   320
#define CIN_ 128
#define HW_  (HH * WW)        // 35840
#define CHUNK 32              // max pixels per queue item (2 rounds of 16)

__device__ __forceinline__ float lrelu(float v) {
    return v >= 0.f ? v : 0.01f * v;
}

// ============================================================================
// K1: stage 1 (per-line grouped 1x1 chain) -> inds1 + xT dump; zeroes qcounts.
// 2 blocks per line (512 thr), 5 tiles of 32 px, 4 chains per wave.
// Layers 2/3 via per-wave ys LDS-broadcast float4; per-output FP accumulation
// order bit-identical to the proven kernel.  [round-12 proven, 181.5us]
// ============================================================================
__global__ __launch_bounds__(512, 2)
void k1_stage1(const float* __restrict__ x_in,
               const float* __restrict__ w1_0, const float* __restrict__ b1_0,
               const float* __restrict__ w1_1, const float* __restrict__ b1_1,
               const float* __restrict__ w1_2, const float* __restrict__ b1_2,
               int* __restrict__ inds1_out, float* __restrict__ xT_out,
               int* __restrict__ qc2, int* __restrict__ qc3)
{
    __shared__ float w1s0[32][CIN_ + 1];
    __shared__ float w1s1[32][33];
    __shared__ float w1s2[16][33];
    __shared__ float b1s[80];
    __shared__ float xT[32][132];          // 32-px tile, float4-aligned rows
    __shared__ float ys[8][4][32];         // [wave][chain][32], wave-private

    const int h   = blockIdx.x >> 1;
    const int q   = blockIdx.x & 1;
    const int tid = threadIdx.x;
    const int base = h * WW;

    if (blockIdx.x == 0 && tid == 0) { *qc2 = 0; *qc3 = 0; }

    for (int n = tid; n < 32 * CIN_; n += 512)
        w1s0[n >> 7][n & 127] = w1_0[h * (32 * CIN_) + n];
    for (int n = tid; n < 32 * 32; n += 512)
        w1s1[n >> 5][n & 31] = w1_1[h * 1024 + n];
    if (tid < 16 * 32)
        w1s2[tid >> 5][tid & 31] = w1_2[h * 512 + tid];
    if      (tid < 32) b1s[tid] = b1_0[h * 32 + tid];
    else if (tid < 64) b1s[tid] = b1_1[h * 32 + (tid - 32)];
    else if (tid < 80) b1s[tid] = b1_2[h * 16 + (tid - 64)];
    __syncthreads();

    const int wave = tid >> 6;
    const int lane = tid & 63;
    const int o    = lane & 31;
    const int half = lane >> 5;
    const int o16  = lane & 15;

    for (int t = 0; t < 5; ++t) {
        const int w0 = q * 160 + t * 32;
        for (int n = tid; n < 32 * CIN_; n += 512) {
            int ww = n & 31, c = n >> 5;
            xT[ww][c] = x_in[c * HW_ + base + w0 + ww];
        }
        __syncthreads();
        for (int n = tid; n < 32 * CIN_; n += 512) {
            int pix = n >> 7, c = n & 127;
            xT_out[(size_t)(base + w0 + pix) * CIN_ + c] = xT[pix][c];
        }

        // ---- layer1 128->32 (weights shared across 4 chains; order exact) ----
        float a0 = 0.f, a1 = 0.f, a2 = 0.f, a3 = 0.f;
        #pragma unroll
        for (int i = 0; i < 64; i += 4) {
            const int ii = half * 64 + i;
            const float w0v = w1s0[o][ii];
            const float w1v = w1s0[o][ii + 1];
            const float w2v = w1s0[o][ii + 2];
            const float w3v = w1s0[o][ii + 3];
            const float4 v0 = *reinterpret_cast<const float4*>(&xT[wave * 4 + 0][ii]);
            const float4 v1 = *reinterpret_cast<const float4*>(&xT[wave * 4 + 1][ii]);
            const float4 v2 = *reinterpret_cast<const float4*>(&xT[wave * 4 + 2][ii]);
            const float4 v3 = *reinterpret_cast<const float4*>(&xT[wave * 4 + 3][ii]);
            a0 += v0.x * w0v; a1 += v1.x * w0v; a2 += v2.x * w0v; a3 += v3.x * w0v;
            a0 += v0.y * w1v; a1 += v1.y * w1v; a2 += v2.y * w1v; a3 += v3.y * w1v;
            a0 += v0.z * w2v; a1 += v1.z * w2v; a2 += v2.z * w2v; a3 += v3.z * w2v;
            a0 += v0.w * w3v; a1 += v1.w * w3v; a2 += v2.w * w3v; a3 += v3.w * w3v;
        }
        a0 += __shfl_xor(a0, 32); a1 += __shfl_xor(a1, 32);
        a2 += __shfl_xor(a2, 32); a3 += __shfl_xor(a3, 32);
        ys[wave][0][o] = lrelu(a0 + b1s[o]);
        ys[wave][1][o] = lrelu(a1 + b1s[o]);
        ys[wave][2][o] = lrelu(a2 + b1s[o]);
        ys[wave][3][o] = lrelu(a3 + b1s[o]);

        // ---- layer2 32->32 via ys broadcast float4 ----
        a0 = a1 = a2 = a3 = 0.f;
        #pragma unroll
        for (int i = 0; i < 32; i += 4) {
            const float w0v = w1s1[o][i];
            const float w1v = w1s1[o][i + 1];
            const float w2v = w1s1[o][i + 2];
            const float w3v = w1s1[o][i + 3];
            const float4 y0 = *reinterpret_cast<const float4*>(&ys[wave][0][i]);
            const float4 y1 = *reinterpret_cast<const float4*>(&ys[wave][1][i]);
            const float4 y2 = *reinterpret_cast<const float4*>(&ys[wave][2][i]);
            const float4 y3 = *reinterpret_cast<const float4*>(&ys[wave][3][i]);
            a0 += y0.x * w0v; a1 += y1.x * w0v; a2 += y2.x * w0v; a3 += y3.x * w0v;
            a0 += y0.y * w1v; a1 += y1.y * w1v; a2 += y2.y * w1v; a3 += y3.y * w1v;
            a0 += y0.z * w2v; a1 += y1.z * w2v; a2 += y2.z * w2v; a3 += y3.z * w2v;
            a0 += y0.w * w3v; a1 += y1.w * w3v; a2 += y2.w * w3v; a3 += y3.w * w3v;
        }
        ys[wave][0][o] = lrelu(a0 + b1s[32 + o]);
        ys[wave][1][o] = lrelu(a1 + b1s[32 + o]);
        ys[wave][2][o] = lrelu(a2 + b1s[32 + o]);
        ys[wave][3][o] = lrelu(a3 + b1s[32 + o]);

        // ---- layer3 32->16 ----
        a0 = a1 = a2 = a3 = 0.f;
        #pragma unroll
        for (int i = 0; i < 32; i += 4) {
            const float w0v = w1s2[o16][i];
            const float w1v = w1s2[o16][i + 1];
            const float w2v = w1s2[o16][i + 2];
            const float w3v = w1s2[o16][i + 3];
            const float4 y0 = *reinterpret_cast<const float4*>(&ys[wave][0][i]);
            const float4 y1 = *reinterpret_cast<const float4*>(&ys[wave][1][i]);
            const float4 y2 = *reinterpret_cast<const float4*>(&ys[wave][2][i]);
            const float4 y3 = *reinterpret_cast<const float4*>(&ys[wave][3][i]);
            a0 += y0.x * w0v; a1 += y1.x * w0v; a2 += y2.x * w0v; a3 += y3.x * w0v;
            a0 += y0.y * w1v; a1 += y1.y * w1v; a2 += y2.y * w1v; a3 += y3.y * w1v;
            a0 += y0.z * w2v; a1 += y1.z * w2v; a2 += y2.z * w2v; a3 += y3.z * w2v;
            a0 += y0.w * w3v; a1 += y1.w * w3v; a2 += y2.w * w3v; a3 += y3.w * w3v;
        }
        float bv0 = a0 + b1s[64 + o16], bv1 = a1 + b1s[64 + o16];
        float bv2 = a2 + b1s[64 + o16], bv3 = a3 + b1s[64 + o16];
        int bi0 = o16, bi1 = o16, bi2 = o16, bi3 = o16;
        #pragma unroll
        for (int d = 1; d < 16; d <<= 1) {
            const float ov0 = __shfl_xor(bv0, d); const int oi0 = __shfl_xor(bi0, d);
            const float ov1 = __shfl_xor(bv1, d); const int oi1 = __shfl_xor(bi1, d);
            const float ov2 = __shfl_xor(bv2, d); const int oi2 = __shfl_xor(bi2, d);
            const float ov3 = __shfl_xor(bv3, d); const int oi3 = __shfl_xor(bi3, d);
            if (ov0 > bv0 || (ov0 == bv0 && oi0 < bi0)) { bv0 = ov0; bi0 = oi0; }
            if (ov1 > bv1 || (ov1 == bv1 && oi1 < bi1)) { bv1 = ov1; bi1 = oi1; }
            if (ov2 > bv2 || (ov2 == bv2 && oi2 < bi2)) { bv2 = ov2; bi2 = oi2; }
            if (ov3 > bv3 || (ov3 == bv3 && oi3 < bi3)) { bv3 = ov3; bi3 = oi3; }
        }
        if (lane == 0) {
            inds1_out[base + w0 + wave * 4 + 0] = bi0;
            inds1_out[base + w0 + wave * 4 + 1] = bi1;
            inds1_out[base + w0 + wave * 4 + 2] = bi2;
            inds1_out[base + w0 + wave * 4 + 3] = bi3;
        }
        __syncthreads();
    }
}

// ============================================================================
// Sorter: one block per line; bucket-sort by (clipped) routing index; emit
// <=CHUNK-pixel work items. Item order nondeterministic, item set + outputs
// deterministic. (round-9/12 proven)
// ============================================================================
template <int BINS>
__global__ void sorter(const int* __restrict__ inds_in, int clipmax,
                       int* __restrict__ sorted, int4* __restrict__ queue,
                       int* __restrict__ qcount)
{
    __shared__ int cnt[BINS];
    __shared__ int scan[BINS];
    __shared__ int rank[BINS];

    const int h = blockIdx.x, tid = threadIdx.x, base = h * WW;
    if (tid < BINS) { cnt[tid] = 0; rank[tid] = 0; }
    __syncthreads();

    int c = -1;
    if (tid < WW) {
        c = inds_in[base + tid];
        c = min(max(c, 0), clipmax);
        atomicAdd(&cnt[c], 1);
    }
    __syncthreads();
    if (tid < BINS) scan[tid] = cnt[tid];
    __syncthreads();
    for (int s = 1; s < BINS; s <<= 1) {
        int v = 0;
        if (tid >= s && tid < BINS) v = scan[tid - s];
        __syncthreads();
        if (tid < BINS) scan[tid] += v;
        __syncthreads();
    }
    if (tid < WW) {
        int pos = (scan[c] - cnt[c]) + atomicAdd(&rank[c], 1);
        sorted[base + pos] = base + tid;          // absolute pixel id
    }
    if (tid < BINS && cnt[tid] > 0) {
        int offc = scan[tid] - cnt[tid];
        for (int s0 = 0; s0 < cnt[tid]; s0 += CHUNK) {
            int qi = atomicAdd(qcount, 1);
            queue[qi] = make_int4(h, tid, base + offc + s0,
                                  min(CHUNK, cnt[tid] - s0));
        }
    }
}

// ============================================================================
// Queue-driven CondMul chain — round-9/12 proven version (post-timing OK).
// 256 threads (4 waves), block-wide items, weights staged in LDS, 4 chains
// per wave interleaved, named scalars only, bit-exact per-pixel FP order.
// ============================================================================
#define QK_ROUND(TB, PA, PB, PC, PD)                                           \
{                                                                              \
    float a0 = 0.f, a1 = 0.f, a2 = 0.f, a3 = 0.f;                              \
    _Pragma("unroll")                                                          \
    for (int i = 0; i < 64; i += 4) {                                          \
        const int ii = half * 64 + i;                                          \
        const float w0v = ws0[(ii + 0) * 32 + o];                              \
        const float w1v = ws0[(ii + 1) * 32 + o];                              \
        const float w2v = ws0[(ii + 2) * 32 + o];                              \
        const float w3v = ws0[(ii + 3) * 32 + o];                              \
        const float4 v0 = *reinterpret_cast<const float4*>(&xbuf[wave*4+0][ii]);\
        const float4 v1 = *reinterpret_cast<const float4*>(&xbuf[wave*4+1][ii]);\
        const float4 v2 = *reinterpret_cast<const float4*>(&xbuf[wave*4+2][ii]);\
        const float4 v3 = *reinterpret_cast<const float4*>(&xbuf[wave*4+3][ii]);\
        a0 += v0.x * w0v; a1 += v1.x * w0v; a2 += v2.x * w0v; a3 += v3.x * w0v;\
        a0 += v0.y * w1v; a1 += v1.y * w1v; a2 += v2.y * w1v; a3 += v3.y * w1v;\
        a0 += v0.z * w2v; a1 += v1.z * w2v; a2 += v2.z * w2v; a3 += v3.z * w2v;\
        a0 += v0.w * w3v; a1 += v1.w * w3v; a2 += v2.w * w3v; a3 += v3.w * w3v;\
    }                                                                          \
    a0 += __shfl_xor(a0, 32); a1 += __shfl_xor(a1, 32);                        \
    a2 += __shfl_xor(a2, 32); a3 += __shfl_xor(a3, 32);                        \
    ys[wave][0][o] = lrelu(a0 + bs[o]);                                        \
    ys[wave][1][o] = lrelu(a1 + bs[o]);                                        \
    ys[wave][2][o] = lrelu(a2 + bs[o]);                                        \
    ys[wave][3][o] = lrelu(a3 + bs[o]);                                        \
    a0 = a1 = a2 = a3 = 0.f;                                                   \
    _Pragma("unroll")                                                          \
    for (int i = 0; i < 32; i += 4) {                                          \
        const float w0v = ws1[(i + 0) * 32 + o];                               \
        const float w1v = ws1[(i + 1) * 32 + o];                               \
        const float w2v = ws1[(i + 2) * 32 + o];                               \
        const float w3v = ws1[(i + 3) * 32 + o];                               \
        const float4 y0 = *reinterpret_cast<const float4*>(&ys[wave][0][i]);   \
        const float4 y1 = *reinterpret_cast<const float4*>(&ys[wave][1][i]);   \
        const float4 y2 = *reinterpret_cast<const float4*>(&ys[wave][2][i]);   \
        const float4 y3 = *reinterpret_cast<const float4*>(&ys[wave][3][i]);   \
        a0 += y0.x * w0v; a1 += y1.x * w0v; a2 += y2.x * w0v; a3 += y3.x * w0v;\
        a0 += y0.y * w1v; a1 += y1.y * w1v; a2 += y2.y * w1v; a3 += y3.y * w1v;\
        a0 += y0.z * w2v; a1 += y1.z * w2v; a2 += y2.z * w2v; a3 += y3.z * w2v;\
        a0 += y0.w * w3v; a1 += y1.w * w3v; a2 += y2.w * w3v; a3 += y3.w * w3v;\
    }                                                                          \
    ys[wave][0][o] = lrelu(a0 + bs[32 + o]);                                   \
    ys[wave][1][o] = lrelu(a1 + bs[32 + o]);                                   \
    ys[wave][2][o] = lrelu(a2 + bs[32 + o]);                                   \
    ys[wave][3][o] = lrelu(a3 + bs[32 + o]);                                   \
    a0 = a1 = a2 = a3 = 0.f;                                                   \
    _Pragma("unroll")                                                          \
    for (int i = 0; i < 32; i += 4) {                                          \
        const float w0v = ws2[(i + 0) * 32 + o];                               \
        const float w1v = ws2[(i + 1) * 32 + o];                               \
        const float w2v = ws2[(i + 2) * 32 + o];                               \
        const float w3v = ws2[(i + 3) * 32 + o];                               \
        const float4 y0 = *reinterpret_cast<const float4*>(&ys[wave][0][i]);   \
        const float4 y1 = *reinterpret_cast<const float4*>(&ys[wave][1][i]);   \
        const float4 y2 = *reinterpret_cast<const float4*>(&ys[wave][2][i]);   \
        const float4 y3 = *reinterpret_cast<const float4*>(&ys[wave][3][i]);   \
        a0 += y0.x * w0v; a1 += y1.x * w0v; a2 += y2.x * w0v; a3 += y3.x * w0v;\
        a0 += y0.y * w1v; a1 += y1.y * w1v; a2 += y2.y * w1v; a3 += y3.y * w1v;\
        a0 += y0.z * w2v; a1 += y1.z * w2v; a2 += y2.z * w2v; a3 += y3.z * w2v;\
        a0 += y0.w * w3v; a1 += y1.w * w3v; a2 += y2.w * w3v; a3 += y3.w * w3v;\
    }                                                                          \
    float bv0 = a0 + bs[64 + o], bv1 = a1 + bs[64 + o];                        \
    float bv2 = a2 + bs[64 + o], bv3 = a3 + bs[64 + o];                        \
    int bi0 = o, bi1 = o, bi2 = o, bi3 = o;                                    \
    _Pragma("unroll")                                                          \
    for (int d = 1; d < 32; d <<= 1) {                                         \
        const float ov0 = __shfl_xor(bv0, d); const int oi0 = __shfl_xor(bi0, d);\
        const float ov1 = __shfl_xor(bv1, d); const int oi1 = __shfl_xor(bi1, d);\
        const float ov2 = __shfl_xor(bv2, d); const int oi2 = __shfl_xor(bi2, d);\
        const float ov3 = __shfl_xor(bv3, d); const int oi3 = __shfl_xor(bi3, d);\
        if (ov0 > bv0 || (ov0 == bv0 && oi0 < bi0)) { bv0 = ov0; bi0 = oi0; }  \
        if (ov1 > bv1 || (ov1 == bv1 && oi1 < bi1)) { bv1 = ov1; bi1 = oi1; }  \
        if (ov2 > bv2 || (ov2 == bv2 && oi2 < bi2)) { bv2 = ov2; bi2 = oi2; }  \
        if (ov3 > bv3 || (ov3 == bv3 && oi3 < bi3)) { bv3 = ov3; bi3 = oi3; }  \
    }                                                                          \
    if (lane == 0) {                                                           \
        const int tb4 = (TB) + wave * 4;                                       \
        if (STAGE == 2) {                                                      \
            if (tb4 + 0 < n) result[PA] = c * 16 + bi0 - 8;                    \
            if (tb4 + 1 < n) result[PB] = c * 16 + bi1 - 8;                    \
            if (tb4 + 2 < n) result[PC] = c * 16 + bi2 - 8;                    \
            if (tb4 + 3 < n) result[PD] = c * 16 + bi3 - 8;                    \
        } else {                                                               \
            if (tb4 + 0 < n) result[PA] = min(max(inds12_in[PA] * 16 + bi0 - 8, 0), 4095); \
            if (tb4 + 1 < n) result[PB] = min(max(inds12_in[PB] * 16 + bi1 - 8, 0), 4095); \
            if (tb4 + 2 < n) result[PC] = min(max(inds12_in[PC] * 16 + bi2 - 8, 0), 4095); \
            if (tb4 + 3 < n) result[PD] = min(max(inds12_in[PD] * 16 + bi3 - 8, 0), 4095); \
        }                                                                      \
    }                                                                          \
}

template <int STAGE>
__global__ __launch_bounds__(256, 4)
void qk_compute(const float* __restrict__ xT_in, const int* __restrict__ sorted,
                const int4* __restrict__ queue, const int* __restrict__ qcount,
                const float* __restrict__ W0, const float* __restrict__ Bb0,
                const float* __restrict__ W1, const float* __restrict__ Bb1,
                const float* __restrict__ W2, const float* __restrict__ Bb2,
                const int* __restrict__ inds12_in, int* __restrict__ result)
{
    __shared__ float ws0[CIN_ * 32];
    __shared__ float ws1[32 * 32];
    __shared__ float ws2[32 * 32];
    __shared__ float bs[96];
    __shared__ float xbuf[16][CIN_];      // [wave*4+chain][128], per-wave private
    __shared__ float ys[4][4][32];        // [wave][chain][32], per-wave private

    const int tid  = threadIdx.x;
    const int wave = tid >> 6;
    const int lane = tid & 63;
    const int o    = lane & 31;
    const int half = lane >> 5;

    const int qn = *qcount;
    for (int qi = blockIdx.x; qi < qn; qi += gridDim.x) {
        const int4 it4   = queue[qi];
        const int  c     = it4.y;
        const int  start = it4.z;
        const int  n     = it4.w;
        const int  key   = (STAGE == 2) ? (it4.x * 16 + c) : (it4.x * 256 + c);
        const int  nr    = (n + 15) >> 4;
        const int  t0    = wave * 4;

        __syncthreads();                  // all waves done with previous item's LDS

        // ---- prefetch round-0 x (named scalars; 1 float2/pixel/lane) ----
        const int pA0 = sorted[start + min(t0 + 0, n - 1)];
        const int pB0 = sorted[start + min(t0 + 1, n - 1)];
        const int pC0 = sorted[start + min(t0 + 2, n - 1)];
        const int pD0 = sorted[start + min(t0 + 3, n - 1)];
        const float2 xA0 = *reinterpret_cast<const float2*>(&xT_in[(size_t)pA0 * CIN_ + 2 * lane]);
        const float2 xB0 = *reinterpret_cast<const float2*>(&xT_in[(size_t)pB0 * CIN_ + 2 * lane]);
        const float2 xC0 = *reinterpret_cast<const float2*>(&xT_in[(size_t)pC0 * CIN_ + 2 * lane]);
        const float2 xD0 = *reinterpret_cast<const float2*>(&xT_in[(size_t)pD0 * CIN_ + 2 * lane]);

        // ---- stage weight chain into LDS (coalesced float4) ----
        for (int i = tid; i < 1024; i += 256)
            ((float4*)ws0)[i] = ((const float4*)(W0 + (size_t)key * 4096))[i];
        ((float4*)ws1)[tid] = ((const float4*)(W1 + (size_t)key * 1024))[tid];
        ((float4*)ws2)[tid] = ((const float4*)(W2 + (size_t)key * 1024))[tid];
        if      (tid < 32) bs[tid] = Bb0[(size_t)key * 32 + tid];
        else if (tid < 64) bs[tid] = Bb1[(size_t)key * 32 + (tid - 32)];
        else if (tid < 96) bs[tid] = Bb2[(size_t)key * 32 + (tid - 64)];
        __syncthreads();

        // ---- round 0: write prefetched x, prefetch round 1 (scalars) ----
        *reinterpret_cast<float2*>(&xbuf[wave * 4 + 0][2 * lane]) = xA0;
        *reinterpret_cast<float2*>(&xbuf[wave * 4 + 1][2 * lane]) = xB0;
        *reinterpret_cast<float2*>(&xbuf[wave * 4 + 2][2 * lane]) = xC0;
        *reinterpret_cast<float2*>(&xbuf[wave * 4 + 3][2 * lane]) = xD0;

        int pA1 = 0, pB1 = 0, pC1 = 0, pD1 = 0;
        float2 xA1 = {0.f, 0.f}, xB1 = {0.f, 0.f}, xC1 = {0.f, 0.f}, xD1 = {0.f, 0.f};
        if (nr == 2) {
            pA1 = sorted[start + min(16 + t0 + 0, n - 1)];
            pB1 = sorted[start + min(16 + t0 + 1, n - 1)];
            pC1 = sorted[start + min(16 + t0 + 2, n - 1)];
            pD1 = sorted[start + min(16 + t0 + 3, n - 1)];
            xA1 = *reinterpret_cast<const float2*>(&xT_in[(size_t)pA1 * CIN_ + 2 * lane]);
            xB1 = *reinterpret_cast<const float2*>(&xT_in[(size_t)pB1 * CIN_ + 2 * lane]);
            xC1 = *reinterpret_cast<const float2*>(&xT_in[(size_t)pC1 * CIN_ + 2 * lane]);
            xD1 = *reinterpret_cast<const float2*>(&xT_in[(size_t)pD1 * CIN_ + 2 * lane]);
        }

        QK_ROUND(0, pA0, pB0, pC0, pD0)

        if (nr == 2) {
            *reinterpret_cast<float2*>(&xbuf[wave * 4 + 0][2 * lane]) = xA1;
            *reinterpret_cast<float2*>(&xbuf[wave * 4 + 1][2 * lane]) = xB1;
            *reinterpret_cast<float2*>(&xbuf[wave * 4 + 2][2 * lane]) = xC1;
            *reinterpret_cast<float2*>(&xbuf[wave * 4 + 3][2 * lane]) = xD1;
            QK_ROUND(16, pA1, pB1, pC1, pD1)
        }
    }
}

// ============================================================================
// Fallback: proven monolithic kernel (only if d_ws too small — not expected).
// ============================================================================
__global__ __launch_bounds__(512, 4)
void reg3_fused(const float* __restrict__ x_in,
                const float* __restrict__ w1_0, const float* __restrict__ b1_0,
                const float* __restrict__ w1_1, const float* __restrict__ b1_1,
                const float* __restrict__ w1_2, const float* __restrict__ b1_2,
                const float* __restrict__ w2_0, const float* __restrict__ b2_0,
                const float* __restrict__ w2_1, const float* __restrict__ b2_1,
                const float* __restrict__ w2_2, const float* __restrict__ b2_2,
                const float* __restrict__ w3_0, const float* __restrict__ b3_0,
                const float* __restrict__ w3_1, const float* __restrict__ b3_1,
                const float* __restrict__ w3_2, const float* __restrict__ b3_2,
                int* __restrict__ out)
{
    __shared__ float xT[8][CIN_ + 1];
    __shared__ float w1s0[32][CIN_ + 1];
    __shared__ float w1s1[32][33];
    __shared__ float w1s2[16][33];
    __shared__ float b1s[80];

    const int h   = blockIdx.x / 40;
    const int w0  = (blockIdx.x % 40) * 8;
    const int tid = threadIdx.x;

    for (int n = tid; n < 8 * CIN_; n += 512) {
        int ww = n & 7, c = n >> 3;
        xT[ww][c] = x_in[c * HW_ + h * WW + w0 + ww];
    }
    for (int n = tid; n < 32 * CIN_; n += 512)
        w1s0[n >> 7][n & 127] = w1_0[h * (32 * CIN_) + n];
    for (int n = tid; n < 32 * 32; n += 512)
        w1s1[n >> 5][n & 31] = w1_1[h * 1024 + n];
    if (tid < 16 * 32)
        w1s2[tid >> 5][tid & 31] = w1_2[h * 512 + tid];
    if      (tid < 32) b1s[tid] = b1_0[h * 32 + tid];
    else if (tid < 64) b1s[tid] = b1_1[h * 32 + (tid - 32)];
    else if (tid < 80) b1s[tid] = b1_2[h * 16 + (tid - 64)];
    __syncthreads();

    const int wave = tid >> 6, lane = tid & 63;
    const int o = lane & 31, half = lane >> 5, o16 = lane & 15;
    const float* xr = &xT[wave][0];

    float acc = 0.f;
    #pragma unroll
    for (int i = 0; i < 64; ++i) { int ii = half * 64 + i; acc += xr[ii] * w1s0[o][ii]; }
    acc += __shfl_xor(acc, 32);
    float y = lrelu(acc + b1s[o]);
    acc = 0.f;
    #pragma unroll
    for (int i = 0; i < 32; ++i) acc += __shfl(y, i) * w1s1[o][i];
    float y2 = lrelu(acc + b1s[32 + o]);
    acc = 0.f;
    #pragma unroll
    for (int i = 0; i < 32; ++i) acc += __shfl(y2, i) * w1s2[o16][i];
    float t1 = acc + b1s[64 + o16];

    float bv = t1; int bi = o16;
    #pragma unroll
    for (int d = 1; d < 16; d <<= 1) {
        float ov = __shfl_xor(bv, d); int oi = __shfl_xor(bi, d);
        if (ov > bv || (ov == bv && oi < bi)) { bv = ov; bi = oi; }
    }
    const int inds1 = bi;
    const int idx1  = inds1 + 16 * h;

    const float* Wp = w2_0 + (size_t)idx1 * (CIN_ * 32);
    acc = 0.f;
    #pragma unroll
    for (int i = 0; i < 64; ++i) { int ii = half * 64 + i; acc += xr[ii] * Wp[ii * 32 + o]; }
    acc += __shfl_xor(acc, 32);
    y = lrelu(acc + b2_0[idx1 * 32 + o]);
    Wp = w2_1 + (size_t)idx1 * 1024;
    acc = 0.f;
    #pragma unroll
    for (int i = 0; i < 32; ++i) acc += __shfl(y, i) * Wp[i * 32 + o];
    y2 = lrelu(acc + b2_1[idx1 * 32 + o]);
    Wp = w2_2 + (size_t)idx1 * 1024;
    acc = 0.f;
    #pragma unroll
    for (int i = 0; i < 32; ++i) acc += __shfl(y2, i) * Wp[i * 32 + o];
    float y3 = acc + b2_2[idx1 * 32 + o];

    bv = y3; bi = o;
    #pragma unroll
    for (int d = 1; d < 32; d <<= 1) {
        float ov = __shfl_xor(bv, d); int oi = __shfl_xor(bi, d);
        if (ov > bv || (ov == bv && oi < bi)) { bv = ov; bi = oi; }
    }
    const int inds2  = bi;
    const int inds12 = inds1 * 16 + inds2 - 8;
    const int clip12 = min(max(inds12, 0), 255);
    const int idx12  = clip12 + 256 * h;

    Wp = w3_0 + (size_t)idx12 * (CIN_ * 32);
    acc = 0.f;
    #pragma unroll
    for (int i = 0; i < 64; ++i) { int ii = half * 64 + i; acc += xr[ii] * Wp[ii * 32 + o]; }
    acc += __shfl_xor(acc, 32);
    y = lrelu(acc + b3_0[idx12 * 32 + o]);
    Wp = w3_1 + (size_t)idx12 * 1024;
    acc = 0.f;
    #pragma unroll
    for (int i = 0; i < 32; ++i) acc += __shfl(y, i) * Wp[i * 32 + o];
    y2 = lrelu(acc + b3_1[idx12 * 32 + o]);
    Wp = w3_2 + (size_t)idx12 * 1024;
    acc = 0.f;
    #pragma unroll
    for (int i = 0; i < 32; ++i) acc += __shfl(y2, i) * Wp[i * 32 + o];
    y3 = acc + b3_2[idx12 * 32 + o];

    bv = y3; bi = o;
    #pragma unroll
    for (int d = 1; d < 32; d <<= 1) {
        float ov = __shfl_xor(bv, d); int oi = __shfl_xor(bi, d);
        if (ov > bv || (ov == bv && oi < bi)) { bv = ov; bi = oi; }
    }
    int inds123 = inds12 * 16 + bi - 8;
    inds123 = min(max(inds123, 0), 4095);
    if (lane == 0) out[h * WW + w0 + wave] = inds123;
}

extern "C" void kernel_launch(void* const* d_in, const int* in_sizes, int n_in,
                              void* d_out, int out_size, void* d_ws, size_t ws_size,
                              hipStream_t stream)
{
    const float* x_in = (const float*)d_in[0];
    const float* w1_0 = (const float*)d_in[1];
    const float* b1_0 = (const float*)d_in[2];
    const float* w1_1 = (const float*)d_in[3];
    const float* b1_1 = (const float*)d_in[4];
    const float* w1_2 = (const float*)d_in[5];
    const float* b1_2 = (const float*)d_in[6];
    const float* w2_0 = (const float*)d_in[7];
    const float* b2_0 = (const float*)d_in[8];
    const float* w2_1 = (const float*)d_in[9];
    const float* b2_1 = (const float*)d_in[10];
    const float* w2_2 = (const float*)d_in[11];
    const float* b2_2 = (const float*)d_in[12];
    const float* w3_0 = (const float*)d_in[13];
    const float* b3_0 = (const float*)d_in[14];
    const float* w3_1 = (const float*)d_in[15];
    const float* b3_1 = (const float*)d_in[16];
    const float* w3_2 = (const float*)d_in[17];
    const float* b3_2 = (const float*)d_in[18];
    int* out = (int*)d_out;

    // ws layout (bytes)
    char* ws = (char*)d_ws;
    int*   inds1_ws  = (int*)(ws + 0);                 // HW ints
    int*   inds12_ws = (int*)(ws + 143360);            // HW ints
    int*   sorted2   = (int*)(ws + 286720);            // HW ints
    int*   sorted3   = (int*)(ws + 430080);            // HW ints
    int*   qc2       = (int*)(ws + 573440);
    int*   qc3       = (int*)(ws + 573444);
    int4*  queue2    = (int4*)(ws + 573456);           // HW entries max
    int4*  queue3    = (int4*)(ws + 1146896);          // HW entries max
    float* xT_ws     = (float*)(ws + 1720336);         // HW*128 floats
    const size_t NEED = 1720336 + (size_t)HW_ * CIN_ * 4;   // ~20.07 MB

    if (ws_size >= NEED) {
        k1_stage1<<<HH * 2, 512, 0, stream>>>(
            x_in, w1_0, b1_0, w1_1, b1_1, w1_2, b1_2,
            inds1_ws, xT_ws, qc2, qc3);
        sorter<16><<<HH, 512, 0, stream>>>(inds1_ws, 15, sorted2, queue2, qc2);
        qk_compute<2><<<2048, 256, 0, stream>>>(
            xT_ws, sorted2, queue2, qc2,
            w2_0, b2_0, w2_1, b2_1, w2_2, b2_2, nullptr, inds12_ws);
        sorter<256><<<HH, 512, 0, stream>>>(inds12_ws, 255, sorted3, queue3, qc3);
        qk_compute<3><<<2048, 256, 0, stream>>>(
            xT_ws, sorted3, queue3, qc3,
            w3_0, b3_0, w3_1, b3_1, w3_2, b3_2, inds12_ws, out);
    } else {
        reg3_fused<<<HH * 40, 512, 0, stream>>>(
            x_in, w1_0, b1_0, w1_1, b1_1, w1_2, b1_2,
            w2_0, b2_0, w2_1, b2_1, w2_2, b2_2,
            w3_0, b3_0, w3_1, b3_1, w3_2, b3_2, out);
    }
}